// Round 4
// baseline (2507.008 us; speedup 1.0000x reference)
//
#include <hip/hip_runtime.h>

#define BBATCH 4
#define CCH 72
#define HROW 256
#define WCOL 256
#define HWSZ (HROW*WCOL)
#define NPC (BBATCH*HROW*WCOL)
#define BNEPS 1e-3f

__device__ __forceinline__ float clip8(float v){ return fminf(fmaxf(v,-8.f),8.f); }

// BN-train: consumer recomputes per-channel scale/shift from producer's sum/sumsq.
__device__ __forceinline__ void get_ss(int c, const float* __restrict__ sum, const float* __restrict__ ssq,
                                       const float* __restrict__ gam, const float* __restrict__ bet,
                                       float& sc, float& sh){
  float mean = sum[c] * (1.0f/(float)NPC);
  float var  = ssq[c] * (1.0f/(float)NPC) - mean*mean;
  sc = gam[c] * rsqrtf(var + BNEPS);
  sh = bet[c] - mean*sc;
}

// ---------------- Pointwise conv (CIN -> 72), fused input BN+clip, output raw + stats ----------
// block = 512 threads = one (b,h) row of 256 px; thread = 9 out-ch x 4 contiguous w.
// acc[9][4]=36 VGPRs -> total live ~75, fits under the allocator's ~88 cap WITHOUT spilling.
// (Round-2/3 lesson: acc[9][8]=72 forced scratch spills (~12GB L2 traffic, 393us); the
// __launch_bounds__ min-waves hint did NOT raise the allocator's target. Shrink instead.)
// og = tid>>6 is wave-uniform -> weight LDS reads broadcast; stats reduce over 64 lanes.
template<int CIN, int RAW>
__global__ __launch_bounds__(512, 4) void k_pw(const float* __restrict__ in,
    float* __restrict__ out, const float* __restrict__ wgt,
    const float* __restrict__ psum, const float* __restrict__ pssq,
    const float* __restrict__ pgam, const float* __restrict__ pbet,
    float* __restrict__ osum, float* __restrict__ ossq)
{
  __shared__ float xs[36*WCOL];         // one 36-channel chunk of the row, fp32 (36KB)
  __shared__ float wlds[8*CIN*12];      // weights [og][c][12], k<9 valid, 16B-aligned groups
  __shared__ float tsc[CIN], tsh[CIN];
  const int tid = threadIdx.x;
  const int b = blockIdx.x >> 8;
  const int h = blockIdx.x & 255;

  if (RAW==0 && tid < CIN) get_ss(tid, psum,pssq,pgam,pbet, tsc[tid], tsh[tid]);

  for (int i = tid; i < 8*CIN*12; i += 512){
    int og = i / (CIN*12);
    int rem = i - og*(CIN*12);
    int c = rem / 12;
    int k = rem - c*12;
    wlds[i] = (k < 9) ? wgt[(og*9+k)*CIN + c] : 0.0f;
  }
  __syncthreads();

  const int wq = tid & 63;   // 4 contiguous w starting at wq*4
  const int og = tid >> 6;   // 9 output channels og*9..og*9+8 (wave-uniform)
  float acc[9][4];
  #pragma unroll
  for (int k=0;k<9;++k){
    #pragma unroll
    for (int j=0;j<4;++j) acc[k][j]=0.f;
  }

  const size_t base_in = (size_t)b*CIN*HWSZ + (size_t)h*WCOL;
  for (int cb = 0; cb < CIN; cb += 36){
    if (cb) __syncthreads();          // xs reuse boundary
    for (int i = tid; i < 36*32; i += 512){
      int c = i >> 5, m = i & 31;
      const float4* p = (const float4*)(in + base_in + (size_t)(cb+c)*HWSZ + m*8);
      float4 v0 = p[0], v1 = p[1];
      if (RAW==0){
        float sc = tsc[cb+c], sh = tsh[cb+c];
        v0.x = clip8(v0.x*sc+sh); v0.y = clip8(v0.y*sc+sh);
        v0.z = clip8(v0.z*sc+sh); v0.w = clip8(v0.w*sc+sh);
        v1.x = clip8(v1.x*sc+sh); v1.y = clip8(v1.y*sc+sh);
        v1.z = clip8(v1.z*sc+sh); v1.w = clip8(v1.w*sc+sh);
      }
      float4* dst = (float4*)&xs[c*WCOL + m*8];
      dst[0] = v0; dst[1] = v1;
    }
    __syncthreads();

    #pragma unroll 2
    for (int c = 0; c < 36; ++c){
      float4 xv4 = *(const float4*)&xs[c*WCOL + wq*4];
      float xv[4] = {xv4.x, xv4.y, xv4.z, xv4.w};
      const float* wp = &wlds[(og*CIN + cb + c)*12];
      float4 wa = *(const float4*)wp;
      float4 wb = *(const float4*)(wp+4);
      float w8 = wp[8];
      float wv[9] = {wa.x,wa.y,wa.z,wa.w, wb.x,wb.y,wb.z,wb.w, w8};
      #pragma unroll
      for (int k=0;k<9;++k){
        #pragma unroll
        for (int j=0;j<4;++j) acc[k][j] = fmaf(wv[k], xv[j], acc[k][j]);
      }
    }
  }

  const size_t base_out = (size_t)b*CCH*HWSZ + (size_t)h*WCOL + (size_t)wq*4;
  #pragma unroll
  for (int k=0;k<9;++k){
    int o = og*9 + k;
    float s=0.f, qq=0.f;
    #pragma unroll
    for (int j=0;j<4;++j){
      s += acc[k][j];
      qq = fmaf(acc[k][j], acc[k][j], qq);
    }
    *(float4*)(out + base_out + (size_t)o*HWSZ) =
        make_float4(acc[k][0],acc[k][1],acc[k][2],acc[k][3]);
    #pragma unroll
    for (int off=32; off; off>>=1){
      s  += __shfl_xor(s, off);
      qq += __shfl_xor(qq, off);
    }
    if (wq == 0){
      atomicAdd(&osum[o], s);
      atomicAdd(&ossq[o], qq);
    }
  }
}

// ---------------- IIR scan along H, fused input BN+ReLU (+optional residual), output raw + stats
// MODE 0: plain; MODE 1: also store transformed input (h0 -> hbuf); MODE 2: add hbuf(h0), store h1 -> hbuf.
template<int MODE>
__global__ __launch_bounds__(256) void k_iir(const float* __restrict__ in, float* __restrict__ out,
    const float* __restrict__ wabc, float* __restrict__ hbuf,
    const float* __restrict__ psum, const float* __restrict__ pssq,
    const float* __restrict__ pgam, const float* __restrict__ pbet,
    float* __restrict__ osum, float* __restrict__ ossq)
{
  const int tid = threadIdx.x;
  const int bc = blockIdx.x;          // b*CCH + c
  const int c = bc % CCH;
  float sc, sh; get_ss(c, psum,pssq,pgam,pbet, sc, sh);
  const float ka = wabc[c], kb = wabc[CCH+c], kcc = wabc[2*CCH+c];
  const size_t base = (size_t)bc*HWSZ + tid;
  float xprev=0.f, yprev=0.f, lsum=0.f, lssq=0.f;

  for (int hb = 0; hb < HROW; hb += 16){
    float x[16];
    #pragma unroll
    for (int j=0;j<16;++j){
      size_t idx = base + (size_t)(hb+j)*WCOL;
      float v = fmaxf(in[idx]*sc + sh, 0.f);
      if (MODE==1) hbuf[idx] = v;
      if (MODE==2){ v += hbuf[idx]; hbuf[idx] = v; }
      x[j] = v;
    }
    if (hb == 0){ xprev = x[0]; yprev = x[0]; }  // y0 = (a+b+c)*x0
    float t[16];
    t[0] = fmaf(ka, x[0], kb*xprev);
    #pragma unroll
    for (int j=1;j<16;++j) t[j] = fmaf(ka, x[j], kb*x[j-1]);
    #pragma unroll
    for (int j=0;j<16;++j){
      yprev = fmaf(kcc, yprev, t[j]);       // 1-FMA dependent chain
      out[base + (size_t)(hb+j)*WCOL] = yprev;
      lsum += yprev; lssq = fmaf(yprev,yprev,lssq);
    }
    xprev = x[15];
  }

  #pragma unroll
  for (int off=32; off; off>>=1){ lsum += __shfl_xor(lsum,off); lssq += __shfl_xor(lssq,off); }
  __shared__ float rs[4], rq[4];
  if ((tid&63)==0){ rs[tid>>6]=lsum; rq[tid>>6]=lssq; }
  __syncthreads();
  if (tid==0){
    atomicAdd(&osum[c], rs[0]+rs[1]+rs[2]+rs[3]);
    atomicAdd(&ossq[c], rq[0]+rq[1]+rq[2]+rq[3]);
  }
}

// ---------------- Depthwise 5-tap along W, fused input BN+clip, output raw + stats ----------
// block = 8 rows x 256 w of one (b,c); thread = 8 contiguous w of one row.
__global__ __launch_bounds__(256) void k_dw(const float* __restrict__ in, float* __restrict__ out,
    const float* __restrict__ wgt,
    const float* __restrict__ psum, const float* __restrict__ pssq,
    const float* __restrict__ pgam, const float* __restrict__ pbet,
    float* __restrict__ osum, float* __restrict__ ossq)
{
  __shared__ float xs[8*264];   // row stride 264, data at col 4+w, zero halo
  __shared__ float rs[4], rq[4];
  const int tid = threadIdx.x;
  const int ht = blockIdx.x & 31;
  const int bc = blockIdx.x >> 5;
  const int c = bc % CCH;
  float sc, sh; get_ss(c, psum,pssq,pgam,pbet, sc, sh);
  const float w0=wgt[c*5+0], w1=wgt[c*5+1], w2=wgt[c*5+2], w3=wgt[c*5+3], w4=wgt[c*5+4];
  const size_t base = (size_t)bc*HWSZ + (size_t)ht*(8*WCOL);

  if (tid < 64){
    int r = tid>>3, k = tid&7;
    xs[r*264 + (k<4 ? k : 256+k)] = 0.f;
  }
  const int r = tid >> 5, m = tid & 31;
  {
    const float4* p = (const float4*)(in + base + (size_t)r*WCOL + m*8);
    float4 v0 = p[0], v1 = p[1];
    v0.x = clip8(v0.x*sc+sh); v0.y = clip8(v0.y*sc+sh);
    v0.z = clip8(v0.z*sc+sh); v0.w = clip8(v0.w*sc+sh);
    v1.x = clip8(v1.x*sc+sh); v1.y = clip8(v1.y*sc+sh);
    v1.z = clip8(v1.z*sc+sh); v1.w = clip8(v1.w*sc+sh);
    float4* dst = (float4*)&xs[r*264 + 4 + m*8];
    dst[0] = v0; dst[1] = v1;
  }
  __syncthreads();
  float lsum=0.f, lssq=0.f;
  {
    const float* row = &xs[r*264 + m*8];
    float4 a0 = *(const float4*)(row+0);
    float4 a1 = *(const float4*)(row+4);
    float4 a2 = *(const float4*)(row+8);
    float4 a3 = *(const float4*)(row+12);
    float v[16] = {a0.x,a0.y,a0.z,a0.w, a1.x,a1.y,a1.z,a1.w,
                   a2.x,a2.y,a2.z,a2.w, a3.x,a3.y,a3.z,a3.w};
    float o[8];
    #pragma unroll
    for (int j=0;j<8;++j){
      float y = w0*v[j+2];
      y = fmaf(w1, v[j+3], y);
      y = fmaf(w2, v[j+4], y);
      y = fmaf(w3, v[j+5], y);
      y = fmaf(w4, v[j+6], y);
      o[j] = y;
      lsum += y; lssq = fmaf(y,y,lssq);
    }
    float4* dst = (float4*)(out + base + (size_t)r*WCOL + m*8);
    dst[0] = make_float4(o[0],o[1],o[2],o[3]);
    dst[1] = make_float4(o[4],o[5],o[6],o[7]);
  }
  #pragma unroll
  for (int off=32; off; off>>=1){ lsum += __shfl_xor(lsum,off); lssq += __shfl_xor(lssq,off); }
  if ((tid&63)==0){ rs[tid>>6]=lsum; rq[tid>>6]=lssq; }
  __syncthreads();
  if (tid==0){
    atomicAdd(&osum[c], rs[0]+rs[1]+rs[2]+rs[3]);
    atomicAdd(&ossq[c], rq[0]+rq[1]+rq[2]+rq[3]);
  }
}

// ---------------- Final: out = h1 + relu(BN(y12)) (fp32 output) ----------------
__global__ __launch_bounds__(256) void k_final(const float* __restrict__ y12, const float* __restrict__ h1,
    float* __restrict__ outp,
    const float* __restrict__ psum, const float* __restrict__ pssq,
    const float* __restrict__ pgam, const float* __restrict__ pbet)
{
  __shared__ float tsc[CCH], tsh[CCH];
  if (threadIdx.x < CCH) get_ss(threadIdx.x, psum,pssq,pgam,pbet, tsc[threadIdx.x], tsh[threadIdx.x]);
  __syncthreads();
  const size_t TOTALQ = (size_t)BBATCH*CCH*HWSZ/4;
  for (size_t q = (size_t)blockIdx.x*blockDim.x + threadIdx.x; q < TOTALQ;
       q += (size_t)gridDim.x*blockDim.x){
    int cch = (int)((q >> 14) % CCH);
    float sc = tsc[cch], sh = tsh[cch];
    float4 a = *(const float4*)(y12 + q*4);
    float4 b = *(const float4*)(h1 + q*4);
    float4 o;
    o.x = fmaxf(a.x*sc+sh, 0.f) + b.x;
    o.y = fmaxf(a.y*sc+sh, 0.f) + b.y;
    o.z = fmaxf(a.z*sc+sh, 0.f) + b.z;
    o.w = fmaxf(a.w*sc+sh, 0.f) + b.w;
    *(float4*)(outp + q*4) = o;
  }
}

extern "C" void kernel_launch(void* const* d_in, const int* in_sizes, int n_in,
                              void* d_out, int out_size, void* d_ws, size_t ws_size,
                              hipStream_t stream)
{
  (void)in_sizes; (void)n_in; (void)out_size;
  const float* x   = (const float*)d_in[0];
  const float* ew  = (const float*)d_in[1];
  const float* eg  = (const float*)d_in[3];
  const float* ebt = (const float*)d_in[4];
  const float* iw  = (const float*)d_in[5];
  const float* ig  = (const float*)d_in[6];
  const float* ibt = (const float*)d_in[7];
  const float* dwt = (const float*)d_in[8];
  const float* dg  = (const float*)d_in[10];
  const float* dbt = (const float*)d_in[11];
  const float* pw  = (const float*)d_in[12];
  const float* pg  = (const float*)d_in[14];
  const float* pbt = (const float*)d_in[15];
  float* outp = (float*)d_out;

  const size_t BUFE = (size_t)BBATCH*CCH*HWSZ;     // 18,874,368 elements
  const size_t BUFB = BUFE*sizeof(float);          // 75.5 MB
  const size_t STATSB = 13*144*sizeof(float);
  char* ws = (char*)d_ws;
  float* A = (float*)ws;
  float* H = (float*)(ws + BUFB);                  // shared h0/h1 buffer
  float* B;
  float* stats;
  if (ws_size >= 3*BUFB + STATSB + 256){
    B = (float*)(ws + 2*BUFB);
    stats = (float*)(ws + 3*BUFB);
  } else {
    // B ping-pong buffer lives in d_out (dead before k_final, which reads A and H only)
    B = (float*)d_out;
    stats = (float*)(ws + 2*BUFB);
  }
  #define SS(s) (stats + (s)*144)
  #define SQ(s) (stats + (s)*144 + 72)

  hipMemsetAsync(stats, 0, STATSB, stream);

  dim3 blk(256);
  dim3 blkpw(512);
  // s0: expand pointwise (fp32 x -> y0 in A), raw stats0
  k_pw<36,1><<<BBATCH*HROW, blkpw, 0, stream>>>(x, A, ew,
      nullptr,nullptr,nullptr,nullptr, SS(0),SQ(0));
  // unit 0
  k_iir<1><<<BBATCH*CCH, blk, 0, stream>>>(A, B, iw+0,   H, SS(0),SQ(0), eg, ebt, SS(1),SQ(1));
  k_dw    <<<BBATCH*CCH*32, blk, 0, stream>>>(B, A, dwt+0,    SS(1),SQ(1), ig+0,   ibt+0,   SS(2),SQ(2));
  k_pw<72,0><<<BBATCH*HROW, blkpw, 0, stream>>>(A, B, pw+0,     SS(2),SQ(2), dg+0,   dbt+0,   SS(3),SQ(3));
  // unit 1
  k_iir<0><<<BBATCH*CCH, blk, 0, stream>>>(B, A, iw+216, nullptr, SS(3),SQ(3), pg+0,  pbt+0,  SS(4),SQ(4));
  k_dw    <<<BBATCH*CCH*32, blk, 0, stream>>>(A, B, dwt+360,  SS(4),SQ(4), ig+72,  ibt+72,  SS(5),SQ(5));
  k_pw<72,0><<<BBATCH*HROW, blkpw, 0, stream>>>(B, A, pw+5184,  SS(5),SQ(5), dg+72,  dbt+72,  SS(6),SQ(6));
  // unit 2 (residual: h1 = h0 + relu(BN(y6)); IIR on h1; h1 kept in H)
  k_iir<2><<<BBATCH*CCH, blk, 0, stream>>>(A, B, iw+432, H, SS(6),SQ(6), pg+72, pbt+72, SS(7),SQ(7));
  k_dw    <<<BBATCH*CCH*32, blk, 0, stream>>>(B, A, dwt+720,  SS(7),SQ(7), ig+144, ibt+144, SS(8),SQ(8));
  k_pw<72,0><<<BBATCH*HROW, blkpw, 0, stream>>>(A, B, pw+10368, SS(8),SQ(8), dg+144, dbt+144, SS(9),SQ(9));
  // unit 3
  k_iir<0><<<BBATCH*CCH, blk, 0, stream>>>(B, A, iw+648, nullptr, SS(9),SQ(9), pg+144, pbt+144, SS(10),SQ(10));
  k_dw    <<<BBATCH*CCH*32, blk, 0, stream>>>(A, B, dwt+1080, SS(10),SQ(10), ig+216, ibt+216, SS(11),SQ(11));
  k_pw<72,0><<<BBATCH*HROW, blkpw, 0, stream>>>(B, A, pw+15552, SS(11),SQ(11), dg+216, dbt+216, SS(12),SQ(12));
  // out = h1 + relu(BN(y12))
  k_final<<<2048, blk, 0, stream>>>(A, H, outp, SS(12),SQ(12), pg+216, pbt+216);
  #undef SS
  #undef SQ
}

// Round 5
// 590.193 us; speedup vs baseline: 4.2478x; 4.2478x over previous
//
#include <hip/hip_runtime.h>

#define BBATCH 4
#define CCH 72
#define HROW 256
#define WCOL 256
#define HWSZ (HROW*WCOL)
#define NPC (BBATCH*HROW*WCOL)
#define BNEPS 1e-3f
#define NSH 64        // stats shards (reduces same-address atomic contention)
#define SST 144       // floats per shard: [0..71]=sum, [72..143]=sumsq

__device__ __forceinline__ float clip8(float v){ return fminf(fmaxf(v,-8.f),8.f); }

// BN-train scale/shift from sharded sum/sumsq. Wave-parallel: lane l reads shard l,
// butterfly-reduce over 64 lanes; all lanes end with the total. c must be wave-uniform.
__device__ __forceinline__ void get_ss_wave(int c, int lane, const float* __restrict__ pstat,
                                            const float* __restrict__ gam, const float* __restrict__ bet,
                                            float& sc, float& sh){
  float s = pstat[lane*SST + c];
  float q = pstat[lane*SST + 72 + c];
  #pragma unroll
  for (int off=32; off; off>>=1){ s += __shfl_xor(s,off); q += __shfl_xor(q,off); }
  float mean = s * (1.0f/(float)NPC);
  float var  = q * (1.0f/(float)NPC) - mean*mean;
  sc = gam[c] * rsqrtf(var + BNEPS);
  sh = bet[c] - mean*sc;
}

// ---------------- Pointwise conv (CIN -> 72), fused input BN+clip, output raw + sharded stats ----
// block = 512 threads = one (b,h) row of 256 px; thread = 9 out-ch x 4 contiguous w.
template<int CIN, int RAW>
__global__ __launch_bounds__(512, 4) void k_pw(const float* __restrict__ in,
    float* __restrict__ out, const float* __restrict__ wgt,
    const float* __restrict__ pstat,
    const float* __restrict__ pgam, const float* __restrict__ pbet,
    float* __restrict__ ostat)
{
  __shared__ float xs[36*WCOL];         // one 36-channel chunk of the row, fp32 (36KB)
  __shared__ float wlds[8*CIN*12];      // weights [og][c][12], k<9 valid, 16B-aligned groups
  __shared__ float tsc[CIN], tsh[CIN];
  const int tid = threadIdx.x;
  const int b = blockIdx.x >> 8;
  const int h = blockIdx.x & 255;

  if (RAW==0 && tid < CIN){
    float s=0.f, q=0.f;
    for (int sh2=0; sh2<NSH; ++sh2){ s += pstat[sh2*SST + tid]; q += pstat[sh2*SST + 72 + tid]; }
    float mean = s * (1.0f/(float)NPC);
    float var  = q * (1.0f/(float)NPC) - mean*mean;
    float scv = pgam[tid] * rsqrtf(var + BNEPS);
    tsc[tid] = scv;
    tsh[tid] = pbet[tid] - mean*scv;
  }

  for (int i = tid; i < 8*CIN*12; i += 512){
    int og = i / (CIN*12);
    int rem = i - og*(CIN*12);
    int c = rem / 12;
    int k = rem - c*12;
    wlds[i] = (k < 9) ? wgt[(og*9+k)*CIN + c] : 0.0f;
  }
  __syncthreads();

  const int wq = tid & 63;   // 4 contiguous w starting at wq*4
  const int og = tid >> 6;   // 9 output channels og*9..og*9+8 (wave-uniform)
  float acc[9][4];
  #pragma unroll
  for (int k=0;k<9;++k){
    #pragma unroll
    for (int j=0;j<4;++j) acc[k][j]=0.f;
  }

  const size_t base_in = (size_t)b*CIN*HWSZ + (size_t)h*WCOL;
  for (int cb = 0; cb < CIN; cb += 36){
    if (cb) __syncthreads();          // xs reuse boundary
    for (int i = tid; i < 36*32; i += 512){
      int c = i >> 5, m = i & 31;
      const float4* p = (const float4*)(in + base_in + (size_t)(cb+c)*HWSZ + m*8);
      float4 v0 = p[0], v1 = p[1];
      if (RAW==0){
        float sc = tsc[cb+c], sh = tsh[cb+c];
        v0.x = clip8(v0.x*sc+sh); v0.y = clip8(v0.y*sc+sh);
        v0.z = clip8(v0.z*sc+sh); v0.w = clip8(v0.w*sc+sh);
        v1.x = clip8(v1.x*sc+sh); v1.y = clip8(v1.y*sc+sh);
        v1.z = clip8(v1.z*sc+sh); v1.w = clip8(v1.w*sc+sh);
      }
      float4* dst = (float4*)&xs[c*WCOL + m*8];
      dst[0] = v0; dst[1] = v1;
    }
    __syncthreads();

    #pragma unroll 2
    for (int c = 0; c < 36; ++c){
      float4 xv4 = *(const float4*)&xs[c*WCOL + wq*4];
      float xv[4] = {xv4.x, xv4.y, xv4.z, xv4.w};
      const float* wp = &wlds[(og*CIN + cb + c)*12];
      float4 wa = *(const float4*)wp;
      float4 wb = *(const float4*)(wp+4);
      float w8 = wp[8];
      float wv[9] = {wa.x,wa.y,wa.z,wa.w, wb.x,wb.y,wb.z,wb.w, w8};
      #pragma unroll
      for (int k=0;k<9;++k){
        #pragma unroll
        for (int j=0;j<4;++j) acc[k][j] = fmaf(wv[k], xv[j], acc[k][j]);
      }
    }
  }

  float* oshard = ostat + (size_t)(blockIdx.x & (NSH-1))*SST;
  const size_t base_out = (size_t)b*CCH*HWSZ + (size_t)h*WCOL + (size_t)wq*4;
  #pragma unroll
  for (int k=0;k<9;++k){
    int o = og*9 + k;
    float s=0.f, qq=0.f;
    #pragma unroll
    for (int j=0;j<4;++j){
      s += acc[k][j];
      qq = fmaf(acc[k][j], acc[k][j], qq);
    }
    *(float4*)(out + base_out + (size_t)o*HWSZ) =
        make_float4(acc[k][0],acc[k][1],acc[k][2],acc[k][3]);
    #pragma unroll
    for (int off=32; off; off>>=1){
      s  += __shfl_xor(s, off);
      qq += __shfl_xor(qq, off);
    }
    if (wq == 0){
      atomicAdd(oshard + o, s);
      atomicAdd(oshard + 72 + o, qq);
    }
  }
}

// ---------------- IIR scan along H, fused input BN+ReLU (+optional residual), sharded stats ----
// MODE 0: plain; MODE 1: also store transformed input (h0 -> hbuf); MODE 2: add hbuf(h0), store h1 -> hbuf.
template<int MODE>
__global__ __launch_bounds__(256) void k_iir(const float* __restrict__ in, float* __restrict__ out,
    const float* __restrict__ wabc, float* __restrict__ hbuf,
    const float* __restrict__ pstat,
    const float* __restrict__ pgam, const float* __restrict__ pbet,
    float* __restrict__ ostat)
{
  const int tid = threadIdx.x;
  const int bc = blockIdx.x;          // b*CCH + c
  const int c = bc % CCH;
  float sc, sh; get_ss_wave(c, tid&63, pstat, pgam, pbet, sc, sh);
  const float ka = wabc[c], kb = wabc[CCH+c], kcc = wabc[2*CCH+c];
  const size_t base = (size_t)bc*HWSZ + tid;
  float xprev=0.f, yprev=0.f, lsum=0.f, lssq=0.f;

  for (int hb = 0; hb < HROW; hb += 16){
    float x[16];
    #pragma unroll
    for (int j=0;j<16;++j){
      size_t idx = base + (size_t)(hb+j)*WCOL;
      float v = fmaxf(in[idx]*sc + sh, 0.f);
      if (MODE==1) hbuf[idx] = v;
      if (MODE==2){ v += hbuf[idx]; hbuf[idx] = v; }
      x[j] = v;
    }
    if (hb == 0){ xprev = x[0]; yprev = x[0]; }  // y0 = (a+b+c)*x0
    float t[16];
    t[0] = fmaf(ka, x[0], kb*xprev);
    #pragma unroll
    for (int j=1;j<16;++j) t[j] = fmaf(ka, x[j], kb*x[j-1]);
    #pragma unroll
    for (int j=0;j<16;++j){
      yprev = fmaf(kcc, yprev, t[j]);       // 1-FMA dependent chain
      out[base + (size_t)(hb+j)*WCOL] = yprev;
      lsum += yprev; lssq = fmaf(yprev,yprev,lssq);
    }
    xprev = x[15];
  }

  #pragma unroll
  for (int off=32; off; off>>=1){ lsum += __shfl_xor(lsum,off); lssq += __shfl_xor(lssq,off); }
  __shared__ float rs[4], rq[4];
  if ((tid&63)==0){ rs[tid>>6]=lsum; rq[tid>>6]=lssq; }
  __syncthreads();
  if (tid==0){
    float* oshard = ostat + (size_t)(blockIdx.x & (NSH-1))*SST;
    atomicAdd(oshard + c,      rs[0]+rs[1]+rs[2]+rs[3]);
    atomicAdd(oshard + 72 + c, rq[0]+rq[1]+rq[2]+rq[3]);
  }
}

// ---------------- Depthwise 5-tap along W, fused input BN+clip, sharded stats ----------
// block = 8 rows x 256 w of one (b,c); thread = 8 contiguous w of one row.
__global__ __launch_bounds__(256) void k_dw(const float* __restrict__ in, float* __restrict__ out,
    const float* __restrict__ wgt,
    const float* __restrict__ pstat,
    const float* __restrict__ pgam, const float* __restrict__ pbet,
    float* __restrict__ ostat)
{
  __shared__ float xs[8*264];   // row stride 264, data at col 4+w, zero halo
  __shared__ float rs[4], rq[4];
  const int tid = threadIdx.x;
  const int ht = blockIdx.x & 31;
  const int bc = blockIdx.x >> 5;
  const int c = bc % CCH;
  float sc, sh; get_ss_wave(c, tid&63, pstat, pgam, pbet, sc, sh);
  const float w0=wgt[c*5+0], w1=wgt[c*5+1], w2=wgt[c*5+2], w3=wgt[c*5+3], w4=wgt[c*5+4];
  const size_t base = (size_t)bc*HWSZ + (size_t)ht*(8*WCOL);

  if (tid < 64){
    int r = tid>>3, k = tid&7;
    xs[r*264 + (k<4 ? k : 256+k)] = 0.f;
  }
  const int r = tid >> 5, m = tid & 31;
  {
    const float4* p = (const float4*)(in + base + (size_t)r*WCOL + m*8);
    float4 v0 = p[0], v1 = p[1];
    v0.x = clip8(v0.x*sc+sh); v0.y = clip8(v0.y*sc+sh);
    v0.z = clip8(v0.z*sc+sh); v0.w = clip8(v0.w*sc+sh);
    v1.x = clip8(v1.x*sc+sh); v1.y = clip8(v1.y*sc+sh);
    v1.z = clip8(v1.z*sc+sh); v1.w = clip8(v1.w*sc+sh);
    float4* dst = (float4*)&xs[r*264 + 4 + m*8];
    dst[0] = v0; dst[1] = v1;
  }
  __syncthreads();
  float lsum=0.f, lssq=0.f;
  {
    const float* row = &xs[r*264 + m*8];
    float4 a0 = *(const float4*)(row+0);
    float4 a1 = *(const float4*)(row+4);
    float4 a2 = *(const float4*)(row+8);
    float4 a3 = *(const float4*)(row+12);
    float v[16] = {a0.x,a0.y,a0.z,a0.w, a1.x,a1.y,a1.z,a1.w,
                   a2.x,a2.y,a2.z,a2.w, a3.x,a3.y,a3.z,a3.w};
    float o[8];
    #pragma unroll
    for (int j=0;j<8;++j){
      float y = w0*v[j+2];
      y = fmaf(w1, v[j+3], y);
      y = fmaf(w2, v[j+4], y);
      y = fmaf(w3, v[j+5], y);
      y = fmaf(w4, v[j+6], y);
      o[j] = y;
      lsum += y; lssq = fmaf(y,y,lssq);
    }
    float4* dst = (float4*)(out + base + (size_t)r*WCOL + m*8);
    dst[0] = make_float4(o[0],o[1],o[2],o[3]);
    dst[1] = make_float4(o[4],o[5],o[6],o[7]);
  }
  #pragma unroll
  for (int off=32; off; off>>=1){ lsum += __shfl_xor(lsum,off); lssq += __shfl_xor(lssq,off); }
  if ((tid&63)==0){ rs[tid>>6]=lsum; rq[tid>>6]=lssq; }
  __syncthreads();
  if (tid==0){
    float* oshard = ostat + (size_t)(blockIdx.x & (NSH-1))*SST;
    atomicAdd(oshard + c,      rs[0]+rs[1]+rs[2]+rs[3]);
    atomicAdd(oshard + 72 + c, rq[0]+rq[1]+rq[2]+rq[3]);
  }
}

// ---------------- Final: out = h1 + relu(BN(y12)) (fp32 output) ----------------
__global__ __launch_bounds__(256) void k_final(const float* __restrict__ y12, const float* __restrict__ h1,
    float* __restrict__ outp,
    const float* __restrict__ pstat,
    const float* __restrict__ pgam, const float* __restrict__ pbet)
{
  __shared__ float tsc[CCH], tsh[CCH];
  if (threadIdx.x < CCH){
    int cc = threadIdx.x;
    float s=0.f, q=0.f;
    for (int sh2=0; sh2<NSH; ++sh2){ s += pstat[sh2*SST + cc]; q += pstat[sh2*SST + 72 + cc]; }
    float mean = s * (1.0f/(float)NPC);
    float var  = q * (1.0f/(float)NPC) - mean*mean;
    float scv = pgam[cc] * rsqrtf(var + BNEPS);
    tsc[cc] = scv;
    tsh[cc] = pbet[cc] - mean*scv;
  }
  __syncthreads();
  const size_t TOTALQ = (size_t)BBATCH*CCH*HWSZ/4;
  for (size_t q = (size_t)blockIdx.x*blockDim.x + threadIdx.x; q < TOTALQ;
       q += (size_t)gridDim.x*blockDim.x){
    int cch = (int)((q >> 14) % CCH);
    float sc = tsc[cch], sh = tsh[cch];
    float4 a = *(const float4*)(y12 + q*4);
    float4 b = *(const float4*)(h1 + q*4);
    float4 o;
    o.x = fmaxf(a.x*sc+sh, 0.f) + b.x;
    o.y = fmaxf(a.y*sc+sh, 0.f) + b.y;
    o.z = fmaxf(a.z*sc+sh, 0.f) + b.z;
    o.w = fmaxf(a.w*sc+sh, 0.f) + b.w;
    *(float4*)(outp + q*4) = o;
  }
}

extern "C" void kernel_launch(void* const* d_in, const int* in_sizes, int n_in,
                              void* d_out, int out_size, void* d_ws, size_t ws_size,
                              hipStream_t stream)
{
  (void)in_sizes; (void)n_in; (void)out_size;
  const float* x   = (const float*)d_in[0];
  const float* ew  = (const float*)d_in[1];
  const float* eg  = (const float*)d_in[3];
  const float* ebt = (const float*)d_in[4];
  const float* iw  = (const float*)d_in[5];
  const float* ig  = (const float*)d_in[6];
  const float* ibt = (const float*)d_in[7];
  const float* dwt = (const float*)d_in[8];
  const float* dg  = (const float*)d_in[10];
  const float* dbt = (const float*)d_in[11];
  const float* pw  = (const float*)d_in[12];
  const float* pg  = (const float*)d_in[14];
  const float* pbt = (const float*)d_in[15];
  float* outp = (float*)d_out;

  const size_t BUFE = (size_t)BBATCH*CCH*HWSZ;     // 18,874,368 elements
  const size_t BUFB = BUFE*sizeof(float);          // 75.5 MB
  const size_t STATSB = (size_t)13*NSH*SST*sizeof(float);  // ~479 KB
  char* ws = (char*)d_ws;
  float* A = (float*)ws;
  float* H = (float*)(ws + BUFB);                  // shared h0/h1 buffer
  float* B;
  float* stats;
  if (ws_size >= 3*BUFB + STATSB + 256){
    B = (float*)(ws + 2*BUFB);
    stats = (float*)(ws + 3*BUFB);
  } else {
    // B ping-pong buffer lives in d_out (dead before k_final, which reads A and H only)
    B = (float*)d_out;
    stats = (float*)(ws + 2*BUFB);
  }
  #define ST(s) (stats + (size_t)(s)*NSH*SST)

  hipMemsetAsync(stats, 0, STATSB, stream);

  dim3 blk(256);
  dim3 blkpw(512);
  // s0: expand pointwise (fp32 x -> y0 in A), raw stats0
  k_pw<36,1><<<BBATCH*HROW, blkpw, 0, stream>>>(x, A, ew,
      nullptr, nullptr, nullptr, ST(0));
  // unit 0
  k_iir<1><<<BBATCH*CCH, blk, 0, stream>>>(A, B, iw+0,   H, ST(0), eg, ebt, ST(1));
  k_dw    <<<BBATCH*CCH*32, blk, 0, stream>>>(B, A, dwt+0,    ST(1), ig+0,   ibt+0,   ST(2));
  k_pw<72,0><<<BBATCH*HROW, blkpw, 0, stream>>>(A, B, pw+0,     ST(2), dg+0,   dbt+0,   ST(3));
  // unit 1
  k_iir<0><<<BBATCH*CCH, blk, 0, stream>>>(B, A, iw+216, nullptr, ST(3), pg+0,  pbt+0,  ST(4));
  k_dw    <<<BBATCH*CCH*32, blk, 0, stream>>>(A, B, dwt+360,  ST(4), ig+72,  ibt+72,  ST(5));
  k_pw<72,0><<<BBATCH*HROW, blkpw, 0, stream>>>(B, A, pw+5184,  ST(5), dg+72,  dbt+72,  ST(6));
  // unit 2 (residual: h1 = h0 + relu(BN(y6)); IIR on h1; h1 kept in H)
  k_iir<2><<<BBATCH*CCH, blk, 0, stream>>>(A, B, iw+432, H, ST(6), pg+72, pbt+72, ST(7));
  k_dw    <<<BBATCH*CCH*32, blk, 0, stream>>>(B, A, dwt+720,  ST(7), ig+144, ibt+144, ST(8));
  k_pw<72,0><<<BBATCH*HROW, blkpw, 0, stream>>>(A, B, pw+10368, ST(8), dg+144, dbt+144, ST(9));
  // unit 3
  k_iir<0><<<BBATCH*CCH, blk, 0, stream>>>(B, A, iw+648, nullptr, ST(9), pg+144, pbt+144, ST(10));
  k_dw    <<<BBATCH*CCH*32, blk, 0, stream>>>(A, B, dwt+1080, ST(10), ig+216, ibt+216, ST(11));
  k_pw<72,0><<<BBATCH*HROW, blkpw, 0, stream>>>(B, A, pw+15552, ST(11), dg+216, dbt+216, ST(12));
  // out = h1 + relu(BN(y12))
  k_final<<<2048, blk, 0, stream>>>(A, H, outp, ST(12), pg+216, pbt+216);
  #undef ST
}

// Round 6
// 460.611 us; speedup vs baseline: 5.4428x; 1.2813x over previous
//
#include <hip/hip_runtime.h>
#include <hip/hip_fp16.h>

#define BBATCH 4
#define CCH 72
#define HROW 256
#define WCOL 256
#define HWSZ (HROW*WCOL)
#define NPC (BBATCH*HROW*WCOL)
#define BNEPS 1e-3f
#define NSH 64        // stats shards (R5: sharding 64x fixed same-address atomic serialization,
                      // k_pw 423us -> 64us; every block previously RMW'd the same 144 addresses)
#define SST 144       // floats per shard: [0..71]=sum, [72..143]=sumsq

typedef unsigned short u16;
typedef unsigned int u32;

__device__ __forceinline__ float h2f(u16 h){ return __half2float(__ushort_as_half(h)); }
__device__ __forceinline__ u16 f2h(float f){ return __half_as_ushort(__float2half(f)); }
__device__ __forceinline__ u32 pack2(float a, float b){ return (u32)f2h(a) | ((u32)f2h(b)<<16); }
__device__ __forceinline__ float clip8(float v){ return fminf(fmaxf(v,-8.f),8.f); }

// BN-train scale/shift from sharded sum/sumsq. Wave-parallel: lane l reads shard l,
// butterfly-reduce over 64 lanes; all lanes end with the total. c must be wave-uniform.
__device__ __forceinline__ void get_ss_wave(int c, int lane, const float* __restrict__ pstat,
                                            const float* __restrict__ gam, const float* __restrict__ bet,
                                            float& sc, float& sh){
  float s = pstat[lane*SST + c];
  float q = pstat[lane*SST + 72 + c];
  #pragma unroll
  for (int off=32; off; off>>=1){ s += __shfl_xor(s,off); q += __shfl_xor(q,off); }
  float mean = s * (1.0f/(float)NPC);
  float var  = q * (1.0f/(float)NPC) - mean*mean;
  sc = gam[c] * rsqrtf(var + BNEPS);
  sh = bet[c] - mean*sc;
}

// ---------------- Pointwise conv (CIN -> 72), fused input BN+clip, fp16 IO, sharded stats ----
// block = 512 threads = one (b,h) row of 256 px; thread = 9 out-ch x 4 contiguous w.
// fp16 LDS x-tile: 18.4KB + fp32 weights 27.6KB -> ~47KB -> 3 blocks/CU (was 2 at fp32/65KB).
template<int CIN, int RAW>
__global__ __launch_bounds__(512, 4) void k_pw(const void* __restrict__ in_,
    u16* __restrict__ out, const float* __restrict__ wgt,
    const float* __restrict__ pstat,
    const float* __restrict__ pgam, const float* __restrict__ pbet,
    float* __restrict__ ostat)
{
  __shared__ u16 xs[36*WCOL];           // one 36-channel chunk of the row, fp16 (18.4KB)
  __shared__ float wlds[8*CIN*12];      // weights [og][c][12], k<9 valid, 16B-aligned groups
  __shared__ float tsc[CIN], tsh[CIN];
  const int tid = threadIdx.x;
  const int b = blockIdx.x >> 8;
  const int h = blockIdx.x & 255;

  if (RAW==0 && tid < CIN){
    float s=0.f, q=0.f;
    for (int sh2=0; sh2<NSH; ++sh2){ s += pstat[sh2*SST + tid]; q += pstat[sh2*SST + 72 + tid]; }
    float mean = s * (1.0f/(float)NPC);
    float var  = q * (1.0f/(float)NPC) - mean*mean;
    float scv = pgam[tid] * rsqrtf(var + BNEPS);
    tsc[tid] = scv;
    tsh[tid] = pbet[tid] - mean*scv;
  }

  for (int i = tid; i < 8*CIN*12; i += 512){
    int og = i / (CIN*12);
    int rem = i - og*(CIN*12);
    int c = rem / 12;
    int k = rem - c*12;
    wlds[i] = (k < 9) ? wgt[(og*9+k)*CIN + c] : 0.0f;
  }
  __syncthreads();

  const int wq = tid & 63;   // 4 contiguous w starting at wq*4
  const int og = tid >> 6;   // 9 output channels og*9..og*9+8 (wave-uniform)
  float acc[9][4];
  #pragma unroll
  for (int k=0;k<9;++k){
    #pragma unroll
    for (int j=0;j<4;++j) acc[k][j]=0.f;
  }

  const size_t base_in = (size_t)b*CIN*HWSZ + (size_t)h*WCOL;
  for (int cb = 0; cb < CIN; cb += 36){
    if (cb) __syncthreads();          // xs reuse boundary
    for (int i = tid; i < 36*32; i += 512){
      int c = i >> 5, m = i & 31;     // m: 8 px
      uint4 pk;
      if (RAW){
        const float4* p = (const float4*)((const float*)in_ + base_in + (size_t)(cb+c)*HWSZ + m*8);
        float4 v0 = p[0], v1 = p[1];
        pk.x = pack2(v0.x, v0.y); pk.y = pack2(v0.z, v0.w);
        pk.z = pack2(v1.x, v1.y); pk.w = pack2(v1.z, v1.w);
      } else {
        uint4 r = *(const uint4*)((const u16*)in_ + base_in + (size_t)(cb+c)*HWSZ + m*8);
        float sc = tsc[cb+c], sh = tsh[cb+c];
        u32 rr[4] = {r.x, r.y, r.z, r.w};
        u32 po[4];
        #pragma unroll
        for (int q=0;q<4;++q){
          float a  = clip8(h2f((u16)rr[q])*sc + sh);
          float bq = clip8(h2f((u16)(rr[q]>>16))*sc + sh);
          po[q] = pack2(a, bq);
        }
        pk.x=po[0]; pk.y=po[1]; pk.z=po[2]; pk.w=po[3];
      }
      *(uint4*)&xs[c*WCOL + m*8] = pk;
    }
    __syncthreads();

    #pragma unroll 2
    for (int c = 0; c < 36; ++c){
      uint2 xp = *(const uint2*)&xs[c*WCOL + wq*4];
      float xv[4] = {h2f((u16)xp.x), h2f((u16)(xp.x>>16)),
                     h2f((u16)xp.y), h2f((u16)(xp.y>>16))};
      const float* wp = &wlds[(og*CIN + cb + c)*12];
      float4 wa = *(const float4*)wp;
      float4 wb = *(const float4*)(wp+4);
      float w8 = wp[8];
      float wv[9] = {wa.x,wa.y,wa.z,wa.w, wb.x,wb.y,wb.z,wb.w, w8};
      #pragma unroll
      for (int k=0;k<9;++k){
        #pragma unroll
        for (int j=0;j<4;++j) acc[k][j] = fmaf(wv[k], xv[j], acc[k][j]);
      }
    }
  }

  float* oshard = ostat + (size_t)(blockIdx.x & (NSH-1))*SST;
  const size_t base_out = (size_t)b*CCH*HWSZ + (size_t)h*WCOL + (size_t)wq*4;
  #pragma unroll
  for (int k=0;k<9;++k){
    int o = og*9 + k;
    float s=0.f, qq=0.f;
    #pragma unroll
    for (int j=0;j<4;++j){
      s += acc[k][j];
      qq = fmaf(acc[k][j], acc[k][j], qq);
    }
    *(uint2*)(out + base_out + (size_t)o*HWSZ) =
        make_uint2(pack2(acc[k][0],acc[k][1]), pack2(acc[k][2],acc[k][3]));
    #pragma unroll
    for (int off=32; off; off>>=1){
      s  += __shfl_xor(s, off);
      qq += __shfl_xor(qq, off);
    }
    if (wq == 0){
      atomicAdd(oshard + o, s);
      atomicAdd(oshard + 72 + o, qq);
    }
  }
}

// ---------------- IIR scan along H, fused input BN+ReLU (+optional residual), fp16 IO ----
// MODE 0: plain; MODE 1: also store transformed input (h0 -> hbuf); MODE 2: add hbuf(h0), store h1 -> hbuf.
template<int MODE>
__global__ __launch_bounds__(256) void k_iir(const u16* __restrict__ in, u16* __restrict__ out,
    const float* __restrict__ wabc, u16* __restrict__ hbuf,
    const float* __restrict__ pstat,
    const float* __restrict__ pgam, const float* __restrict__ pbet,
    float* __restrict__ ostat)
{
  const int tid = threadIdx.x;
  const int bc = blockIdx.x;          // b*CCH + c
  const int c = bc % CCH;
  float sc, sh; get_ss_wave(c, tid&63, pstat, pgam, pbet, sc, sh);
  const float ka = wabc[c], kb = wabc[CCH+c], kcc = wabc[2*CCH+c];
  const size_t base = (size_t)bc*HWSZ + tid;
  float xprev=0.f, yprev=0.f, lsum=0.f, lssq=0.f;

  for (int hb = 0; hb < HROW; hb += 16){
    float x[16];
    #pragma unroll
    for (int j=0;j<16;++j){
      size_t idx = base + (size_t)(hb+j)*WCOL;
      float v = fmaxf(h2f(in[idx])*sc + sh, 0.f);
      if (MODE==1) hbuf[idx] = f2h(v);
      if (MODE==2){ v += h2f(hbuf[idx]); hbuf[idx] = f2h(v); }
      x[j] = v;
    }
    if (hb == 0){ xprev = x[0]; yprev = x[0]; }  // y0 = (a+b+c)*x0
    float t[16];
    t[0] = fmaf(ka, x[0], kb*xprev);
    #pragma unroll
    for (int j=1;j<16;++j) t[j] = fmaf(ka, x[j], kb*x[j-1]);
    #pragma unroll
    for (int j=0;j<16;++j){
      yprev = fmaf(kcc, yprev, t[j]);       // 1-FMA dependent chain
      out[base + (size_t)(hb+j)*WCOL] = f2h(yprev);
      lsum += yprev; lssq = fmaf(yprev,yprev,lssq);
    }
    xprev = x[15];
  }

  #pragma unroll
  for (int off=32; off; off>>=1){ lsum += __shfl_xor(lsum,off); lssq += __shfl_xor(lssq,off); }
  __shared__ float rs[4], rq[4];
  if ((tid&63)==0){ rs[tid>>6]=lsum; rq[tid>>6]=lssq; }
  __syncthreads();
  if (tid==0){
    float* oshard = ostat + (size_t)(blockIdx.x & (NSH-1))*SST;
    atomicAdd(oshard + c,      rs[0]+rs[1]+rs[2]+rs[3]);
    atomicAdd(oshard + 72 + c, rq[0]+rq[1]+rq[2]+rq[3]);
  }
}

// ---------------- Depthwise 5-tap along W, fused input BN+clip, fp16 IO ----------
// block = 8 rows x 256 w of one (b,c); thread = 8 contiguous w of one row.
__global__ __launch_bounds__(256) void k_dw(const u16* __restrict__ in, u16* __restrict__ out,
    const float* __restrict__ wgt,
    const float* __restrict__ pstat,
    const float* __restrict__ pgam, const float* __restrict__ pbet,
    float* __restrict__ ostat)
{
  __shared__ float xs[8*264];   // row stride 264, data at col 4+w, zero halo (fp32 internal)
  __shared__ float rs[4], rq[4];
  const int tid = threadIdx.x;
  const int ht = blockIdx.x & 31;
  const int bc = blockIdx.x >> 5;
  const int c = bc % CCH;
  float sc, sh; get_ss_wave(c, tid&63, pstat, pgam, pbet, sc, sh);
  const float w0=wgt[c*5+0], w1=wgt[c*5+1], w2=wgt[c*5+2], w3=wgt[c*5+3], w4=wgt[c*5+4];
  const size_t base = (size_t)bc*HWSZ + (size_t)ht*(8*WCOL);

  if (tid < 64){
    int r = tid>>3, k = tid&7;
    xs[r*264 + (k<4 ? k : 256+k)] = 0.f;
  }
  const int r = tid >> 5, m = tid & 31;
  {
    uint4 v = *(const uint4*)(in + base + (size_t)r*WCOL + m*8);
    u32 rr[4] = {v.x, v.y, v.z, v.w};
    float f[8];
    #pragma unroll
    for (int q=0;q<4;++q){
      f[2*q]   = clip8(h2f((u16)rr[q])*sc + sh);
      f[2*q+1] = clip8(h2f((u16)(rr[q]>>16))*sc + sh);
    }
    float4* dst = (float4*)&xs[r*264 + 4 + m*8];
    dst[0] = make_float4(f[0],f[1],f[2],f[3]);
    dst[1] = make_float4(f[4],f[5],f[6],f[7]);
  }
  __syncthreads();
  float lsum=0.f, lssq=0.f;
  {
    const float* row = &xs[r*264 + m*8];
    float4 a0 = *(const float4*)(row+0);
    float4 a1 = *(const float4*)(row+4);
    float4 a2 = *(const float4*)(row+8);
    float4 a3 = *(const float4*)(row+12);
    float v[16] = {a0.x,a0.y,a0.z,a0.w, a1.x,a1.y,a1.z,a1.w,
                   a2.x,a2.y,a2.z,a2.w, a3.x,a3.y,a3.z,a3.w};
    float o[8];
    #pragma unroll
    for (int j=0;j<8;++j){
      float y = w0*v[j+2];
      y = fmaf(w1, v[j+3], y);
      y = fmaf(w2, v[j+4], y);
      y = fmaf(w3, v[j+5], y);
      y = fmaf(w4, v[j+6], y);
      o[j] = y;
      lsum += y; lssq = fmaf(y,y,lssq);
    }
    *(uint4*)(out + base + (size_t)r*WCOL + m*8) =
        make_uint4(pack2(o[0],o[1]), pack2(o[2],o[3]), pack2(o[4],o[5]), pack2(o[6],o[7]));
  }
  #pragma unroll
  for (int off=32; off; off>>=1){ lsum += __shfl_xor(lsum,off); lssq += __shfl_xor(lssq,off); }
  if ((tid&63)==0){ rs[tid>>6]=lsum; rq[tid>>6]=lssq; }
  __syncthreads();
  if (tid==0){
    float* oshard = ostat + (size_t)(blockIdx.x & (NSH-1))*SST;
    atomicAdd(oshard + c,      rs[0]+rs[1]+rs[2]+rs[3]);
    atomicAdd(oshard + 72 + c, rq[0]+rq[1]+rq[2]+rq[3]);
  }
}

// ---------------- Final: out = h1 + relu(BN(y12)) (fp32 output) ----------------
__global__ __launch_bounds__(256) void k_final(const u16* __restrict__ y12, const u16* __restrict__ h1,
    float* __restrict__ outp,
    const float* __restrict__ pstat,
    const float* __restrict__ pgam, const float* __restrict__ pbet)
{
  __shared__ float tsc[CCH], tsh[CCH];
  if (threadIdx.x < CCH){
    int cc = threadIdx.x;
    float s=0.f, q=0.f;
    for (int sh2=0; sh2<NSH; ++sh2){ s += pstat[sh2*SST + cc]; q += pstat[sh2*SST + 72 + cc]; }
    float mean = s * (1.0f/(float)NPC);
    float var  = q * (1.0f/(float)NPC) - mean*mean;
    float scv = pgam[cc] * rsqrtf(var + BNEPS);
    tsc[cc] = scv;
    tsh[cc] = pbet[cc] - mean*scv;
  }
  __syncthreads();
  const size_t TOTALQ = (size_t)BBATCH*CCH*HWSZ/4;
  for (size_t q = (size_t)blockIdx.x*blockDim.x + threadIdx.x; q < TOTALQ;
       q += (size_t)gridDim.x*blockDim.x){
    int cch = (int)((q >> 14) % CCH);
    float sc = tsc[cch], sh = tsh[cch];
    uint2 a = *(const uint2*)(y12 + q*4);
    uint2 b = *(const uint2*)(h1 + q*4);
    float4 o;
    o.x = fmaxf(h2f((u16)a.x)*sc+sh, 0.f)       + h2f((u16)b.x);
    o.y = fmaxf(h2f((u16)(a.x>>16))*sc+sh, 0.f) + h2f((u16)(b.x>>16));
    o.z = fmaxf(h2f((u16)a.y)*sc+sh, 0.f)       + h2f((u16)b.y);
    o.w = fmaxf(h2f((u16)(a.y>>16))*sc+sh, 0.f) + h2f((u16)(b.y>>16));
    *(float4*)(outp + q*4) = o;
  }
}

extern "C" void kernel_launch(void* const* d_in, const int* in_sizes, int n_in,
                              void* d_out, int out_size, void* d_ws, size_t ws_size,
                              hipStream_t stream)
{
  (void)in_sizes; (void)n_in; (void)out_size;
  const float* x   = (const float*)d_in[0];
  const float* ew  = (const float*)d_in[1];
  const float* eg  = (const float*)d_in[3];
  const float* ebt = (const float*)d_in[4];
  const float* iw  = (const float*)d_in[5];
  const float* ig  = (const float*)d_in[6];
  const float* ibt = (const float*)d_in[7];
  const float* dwt = (const float*)d_in[8];
  const float* dg  = (const float*)d_in[10];
  const float* dbt = (const float*)d_in[11];
  const float* pw  = (const float*)d_in[12];
  const float* pg  = (const float*)d_in[14];
  const float* pbt = (const float*)d_in[15];
  float* outp = (float*)d_out;

  const size_t BUFE = (size_t)BBATCH*CCH*HWSZ;     // 18,874,368 elements
  const size_t BUFB = BUFE*2;                      // fp16: 37.75 MB per buffer
  const size_t STATSB = (size_t)13*NSH*SST*sizeof(float);  // ~479 KB
  char* ws = (char*)d_ws;
  u16* A = (u16*)ws;
  u16* H = (u16*)(ws + BUFB);                      // shared h0/h1 buffer
  u16* B;
  float* stats;
  if (ws_size >= 3*BUFB + STATSB + 256){
    B = (u16*)(ws + 2*BUFB);
    stats = (float*)(ws + 3*BUFB);
  } else {
    // B ping-pong buffer lives in d_out (dead before k_final, which reads A and H only)
    B = (u16*)d_out;
    stats = (float*)(ws + 2*BUFB);
  }
  #define ST(s) (stats + (size_t)(s)*NSH*SST)

  hipMemsetAsync(stats, 0, STATSB, stream);

  dim3 blk(256);
  dim3 blkpw(512);
  // s0: expand pointwise (fp32 x -> y0 in A), raw stats0
  k_pw<36,1><<<BBATCH*HROW, blkpw, 0, stream>>>((const void*)x, A, ew,
      nullptr, nullptr, nullptr, ST(0));
  // unit 0
  k_iir<1><<<BBATCH*CCH, blk, 0, stream>>>(A, B, iw+0,   H, ST(0), eg, ebt, ST(1));
  k_dw    <<<BBATCH*CCH*32, blk, 0, stream>>>(B, A, dwt+0,    ST(1), ig+0,   ibt+0,   ST(2));
  k_pw<72,0><<<BBATCH*HROW, blkpw, 0, stream>>>(A, B, pw+0,     ST(2), dg+0,   dbt+0,   ST(3));
  // unit 1
  k_iir<0><<<BBATCH*CCH, blk, 0, stream>>>(B, A, iw+216, nullptr, ST(3), pg+0,  pbt+0,  ST(4));
  k_dw    <<<BBATCH*CCH*32, blk, 0, stream>>>(A, B, dwt+360,  ST(4), ig+72,  ibt+72,  ST(5));
  k_pw<72,0><<<BBATCH*HROW, blkpw, 0, stream>>>(B, A, pw+5184,  ST(5), dg+72,  dbt+72,  ST(6));
  // unit 2 (residual: h1 = h0 + relu(BN(y6)); IIR on h1; h1 kept in H)
  k_iir<2><<<BBATCH*CCH, blk, 0, stream>>>(A, B, iw+432, H, ST(6), pg+72, pbt+72, ST(7));
  k_dw    <<<BBATCH*CCH*32, blk, 0, stream>>>(B, A, dwt+720,  ST(7), ig+144, ibt+144, ST(8));
  k_pw<72,0><<<BBATCH*HROW, blkpw, 0, stream>>>(A, B, pw+10368, ST(8), dg+144, dbt+144, ST(9));
  // unit 3
  k_iir<0><<<BBATCH*CCH, blk, 0, stream>>>(B, A, iw+648, nullptr, ST(9), pg+144, pbt+144, ST(10));
  k_dw    <<<BBATCH*CCH*32, blk, 0, stream>>>(A, B, dwt+1080, ST(10), ig+216, ibt+216, ST(11));
  k_pw<72,0><<<BBATCH*HROW, blkpw, 0, stream>>>(B, A, pw+15552, ST(11), dg+216, dbt+216, ST(12));
  // out = h1 + relu(BN(y12))
  k_final<<<2048, blk, 0, stream>>>(A, H, outp, ST(12), pg+216, pbt+216);
  #undef ST
}

// Round 8
// 452.228 us; speedup vs baseline: 5.5437x; 1.0185x over previous
//
#include <hip/hip_runtime.h>
#include <hip/hip_fp16.h>

#define BBATCH 4
#define CCH 72
#define HROW 256
#define WCOL 256
#define HWSZ (HROW*WCOL)
#define NPC (BBATCH*HROW*WCOL)
#define BNEPS 1e-3f
#define NSH 64        // stats shards (R5: fixes same-address atomic serialization)
#define SST 144       // floats per shard: [0..71]=sum, [72..143]=sumsq

typedef unsigned short u16;
typedef unsigned int u32;
typedef _Float16 h8 __attribute__((ext_vector_type(8)));
typedef float f32x4 __attribute__((ext_vector_type(4)));

__device__ __forceinline__ float h2f(u16 h_){ return __half2float(__ushort_as_half(h_)); }
__device__ __forceinline__ u16 f2h(float f){ return __half_as_ushort(__float2half(f)); }
__device__ __forceinline__ u32 pack2(float a, float b){ return (u32)f2h(a) | ((u32)f2h(b)<<16); }
__device__ __forceinline__ float clip8(float v){ return fminf(fmaxf(v,-8.f),8.f); }

// BN-train scale/shift from sharded sum/sumsq (wave-parallel butterfly). c wave-uniform.
__device__ __forceinline__ void get_ss_wave(int c, int lane, const float* __restrict__ pstat,
                                            const float* __restrict__ gam, const float* __restrict__ bet,
                                            float& sc, float& sh){
  float s = pstat[lane*SST + c];
  float q = pstat[lane*SST + 72 + c];
  #pragma unroll
  for (int off=32; off; off>>=1){ s += __shfl_xor(s,off); q += __shfl_xor(q,off); }
  float mean = s * (1.0f/(float)NPC);
  float var  = q * (1.0f/(float)NPC) - mean*mean;
  sc = gam[c] * rsqrtf(var + BNEPS);
  sh = bet[c] - mean*sc;
}

// ---------------- Pointwise conv (CIN -> 72) via MFMA 16x16x32_f16 ----------------
// Per (b,h) row: Y(72x256) = W(72xCIN) X(CINx256). M-pad 80 (5 tiles), K-pad to KB*32.
// 8 waves; wave owns pxtile wid of each 128-px half, all 5 M-tiles: acc[5][2].
// A: Wh/Wl[kb][row][40-pad], lane reads 8 contiguous k at [mt*16+li][g*8] (b128).
// B: xs[buf][pxtile][c][16]; lane reads 8 SCALAR u16 at [wid][g*8+j][li] (R7 post-mortem:
//    the ds_read_b64_tr_b16 inline-asm variant failed absmax 15 — ambiguous lane/elem
//    semantics; scalar compiler-generated reads are mapping-identical and unambiguous).
// Weights split hi+lo fp16 (2 MFMAs) -> weight quantization negligible.
// Stats: LDS pre-combine -> 1 global atomic per channel per block (R5-proven level).
template<int CIN, int RAW>
__global__ __launch_bounds__(512) void k_pw(const void* __restrict__ in_,
    u16* __restrict__ out, const float* __restrict__ wgt,
    const float* __restrict__ pstat,
    const float* __restrict__ pgam, const float* __restrict__ pbet,
    float* __restrict__ ostat)
{
  constexpr int KB  = (CIN + 31) / 32;   // K-steps of 32
  constexpr int NPH = 2 * KB;            // phases = halves x K-steps
  __shared__ u16 Wh[KB][80][40];
  __shared__ u16 Wl[KB][80][40];
  __shared__ u16 xs[2][8][32][16];       // [buf][pxtile][c_local][px_in_tile]
  __shared__ float tsc[CIN], tsh[CIN];
  __shared__ float sst[72], sqt[72];

  const int tid  = threadIdx.x;
  const int lane = tid & 63;
  const int wid  = tid >> 6;             // wave id 0..7 = pxtile
  const int g    = lane >> 4;            // 16-lane group -> k-octet
  const int li   = lane & 15;
  const int b    = blockIdx.x >> 8;
  const int hrow = blockIdx.x & 255;

  if (tid < 72){ sst[tid] = 0.f; sqt[tid] = 0.f; }
  if (RAW==0 && tid < CIN){
    float s=0.f, q=0.f;
    for (int sh2=0; sh2<NSH; ++sh2){ s += pstat[sh2*SST + tid]; q += pstat[sh2*SST + 72 + tid]; }
    float mean = s * (1.0f/(float)NPC);
    float var  = q * (1.0f/(float)NPC) - mean*mean;
    float scv = pgam[tid] * rsqrtf(var + BNEPS);
    tsc[tid] = scv;
    tsh[tid] = pbet[tid] - mean*scv;
  }

  // ---- stage weights (hi/lo split), zero-padded ----
  for (int e = tid; e < KB*80*40; e += 512){
    int kb  = e / 3200;
    int rem = e - kb*3200;
    int row = rem / 40;
    int col = rem - row*40;
    int c   = kb*32 + col;
    float w = 0.f;
    if (row < 72 && col < 32 && c < CIN) w = wgt[row*CIN + c];
    u16 hi = f2h(w);
    Wh[kb][row][col] = hi;
    Wl[kb][row][col] = f2h(w - h2f(hi));
  }

  // ---- staging geometry: thread = (c_local, px-octet) ----
  const int c_l = tid >> 4;              // 0..31
  const int o8  = tid & 15;              // px octet within 128-px half
  const int pxt = o8 >> 1;
  const int pp  = (o8 & 1) * 8;
  float xf[8];

  auto LOADP = [&](int p){
    int half = p / KB, kb = p - half*KB;
    int c = kb*32 + c_l;
    int px = half*128 + o8*8;
    if (c < CIN){
      if (RAW){
        const float* ip = (const float*)in_ + (size_t)b*CIN*HWSZ + (size_t)c*HWSZ + hrow*WCOL + px;
        float4 v0 = *(const float4*)ip;
        float4 v1 = *(const float4*)(ip+4);
        xf[0]=v0.x; xf[1]=v0.y; xf[2]=v0.z; xf[3]=v0.w;
        xf[4]=v1.x; xf[5]=v1.y; xf[6]=v1.z; xf[7]=v1.w;
      } else {
        const u16* ip = (const u16*)in_ + (size_t)b*CIN*HWSZ + (size_t)c*HWSZ + hrow*WCOL + px;
        uint4 r = *(const uint4*)ip;
        xf[0]=h2f((u16)r.x); xf[1]=h2f((u16)(r.x>>16));
        xf[2]=h2f((u16)r.y); xf[3]=h2f((u16)(r.y>>16));
        xf[4]=h2f((u16)r.z); xf[5]=h2f((u16)(r.z>>16));
        xf[6]=h2f((u16)r.w); xf[7]=h2f((u16)(r.w>>16));
      }
    } else {
      #pragma unroll
      for (int j=0;j<8;++j) xf[j]=0.f;
    }
  };

  auto WRITEP = [&](int p){
    int kb = p % KB;
    int c = kb*32 + c_l;
    float v[8];
    if (RAW==0){
      float s = (c < CIN) ? tsc[c] : 1.f;
      float t = (c < CIN) ? tsh[c] : 0.f;
      #pragma unroll
      for (int j=0;j<8;++j) v[j] = clip8(xf[j]*s + t);
    } else {
      #pragma unroll
      for (int j=0;j<8;++j) v[j] = xf[j];
    }
    uint4 pk;
    pk.x = pack2(v[0],v[1]); pk.y = pack2(v[2],v[3]);
    pk.z = pack2(v[4],v[5]); pk.w = pack2(v[6],v[7]);
    *(uint4*)&xs[p&1][pxt][c_l][pp] = pk;
  };

  f32x4 acc[5][2];
  #pragma unroll
  for (int mt=0; mt<5; ++mt)
    #pragma unroll
    for (int hf=0; hf<2; ++hf)
      acc[mt][hf] = (f32x4){0.f,0.f,0.f,0.f};

  LOADP(0);
  __syncthreads();   // W, tsc/tsh, stats-init ready

  #pragma unroll
  for (int p = 0; p < NPH; ++p){
    WRITEP(p);
    if (p+1 < NPH) LOADP(p+1);
    __syncthreads();
    // ---- compute phase p (half, kb, buffer index all compile-time) ----
    {
      constexpr int dummy = 0; (void)dummy;
      const int half = p / KB, kb = p - half*KB;
      h8 bf;
      #pragma unroll
      for (int j=0;j<8;++j)
        bf[j] = *(const _Float16*)&xs[p&1][wid][g*8+j][li];
      #pragma unroll
      for (int mt=0; mt<5; ++mt){
        h8 ah = *(const h8*)&Wh[kb][mt*16 + li][g*8];
        h8 al = *(const h8*)&Wl[kb][mt*16 + li][g*8];
        f32x4 a = acc[mt][half];
        a = __builtin_amdgcn_mfma_f32_16x16x32_f16(ah, bf, a, 0, 0, 0);
        a = __builtin_amdgcn_mfma_f32_16x16x32_f16(al, bf, a, 0, 0, 0);
        acc[mt][half] = a;
      }
    }
    // single barrier per phase: next iter writes the OTHER buffer; a buffer is
    // only rewritten after the barrier that every wave reaches post-compute.
  }

  // ---- epilogue: stores + stats (D layout m89: col=lane&15 -> px, row=g*4+r -> out-ch) ----
  #pragma unroll
  for (int mt=0; mt<5; ++mt){
    #pragma unroll
    for (int r=0; r<4; ++r){
      int o = mt*16 + g*4 + r;
      float s = 0.f, q = 0.f;
      #pragma unroll
      for (int hf=0; hf<2; ++hf){
        float y = acc[mt][hf][r];
        if (o < 72){
          int px = hf*128 + wid*16 + li;
          out[(size_t)b*CCH*HWSZ + (size_t)o*HWSZ + hrow*WCOL + px] = f2h(y);
        }
        s += y; q = fmaf(y,y,q);
      }
      s += __shfl_xor(s,1); q += __shfl_xor(q,1);
      s += __shfl_xor(s,2); q += __shfl_xor(q,2);
      s += __shfl_xor(s,4); q += __shfl_xor(q,4);
      s += __shfl_xor(s,8); q += __shfl_xor(q,8);
      if (li == 0 && o < 72){
        atomicAdd(&sst[o], s);
        atomicAdd(&sqt[o], q);
      }
    }
  }
  __syncthreads();
  if (tid < 72){
    float* oshard = ostat + (size_t)(blockIdx.x & (NSH-1))*SST;
    atomicAdd(oshard + tid,      sst[tid]);
    atomicAdd(oshard + 72 + tid, sqt[tid]);
  }
}

// ---------------- IIR scan along H, fused input BN+ReLU (+optional residual), fp16 IO ----
template<int MODE>
__global__ __launch_bounds__(256) void k_iir(const u16* __restrict__ in, u16* __restrict__ out,
    const float* __restrict__ wabc, u16* __restrict__ hbuf,
    const float* __restrict__ pstat,
    const float* __restrict__ pgam, const float* __restrict__ pbet,
    float* __restrict__ ostat)
{
  const int tid = threadIdx.x;
  const int bc = blockIdx.x;          // b*CCH + c
  const int c = bc % CCH;
  float sc, sh; get_ss_wave(c, tid&63, pstat, pgam, pbet, sc, sh);
  const float ka = wabc[c], kb = wabc[CCH+c], kcc = wabc[2*CCH+c];
  const size_t base = (size_t)bc*HWSZ + tid;
  float xprev=0.f, yprev=0.f, lsum=0.f, lssq=0.f;

  for (int hb = 0; hb < HROW; hb += 16){
    float x[16];
    #pragma unroll
    for (int j=0;j<16;++j){
      size_t idx = base + (size_t)(hb+j)*WCOL;
      float v = fmaxf(h2f(in[idx])*sc + sh, 0.f);
      if (MODE==1) hbuf[idx] = f2h(v);
      if (MODE==2){ v += h2f(hbuf[idx]); hbuf[idx] = f2h(v); }
      x[j] = v;
    }
    if (hb == 0){ xprev = x[0]; yprev = x[0]; }  // y0 = (a+b+c)*x0
    float t[16];
    t[0] = fmaf(ka, x[0], kb*xprev);
    #pragma unroll
    for (int j=1;j<16;++j) t[j] = fmaf(ka, x[j], kb*x[j-1]);
    #pragma unroll
    for (int j=0;j<16;++j){
      yprev = fmaf(kcc, yprev, t[j]);       // 1-FMA dependent chain
      out[base + (size_t)(hb+j)*WCOL] = f2h(yprev);
      lsum += yprev; lssq = fmaf(yprev,yprev,lssq);
    }
    xprev = x[15];
  }

  #pragma unroll
  for (int off=32; off; off>>=1){ lsum += __shfl_xor(lsum,off); lssq += __shfl_xor(lssq,off); }
  __shared__ float rs[4], rq[4];
  if ((tid&63)==0){ rs[tid>>6]=lsum; rq[tid>>6]=lssq; }
  __syncthreads();
  if (tid==0){
    float* oshard = ostat + (size_t)(blockIdx.x & (NSH-1))*SST;
    atomicAdd(oshard + c,      rs[0]+rs[1]+rs[2]+rs[3]);
    atomicAdd(oshard + 72 + c, rq[0]+rq[1]+rq[2]+rq[3]);
  }
}

// ---------------- Depthwise 5-tap along W, fused input BN+clip, fp16 IO ----------
__global__ __launch_bounds__(256) void k_dw(const u16* __restrict__ in, u16* __restrict__ out,
    const float* __restrict__ wgt,
    const float* __restrict__ pstat,
    const float* __restrict__ pgam, const float* __restrict__ pbet,
    float* __restrict__ ostat)
{
  __shared__ float xs[8*264];   // row stride 264, data at col 4+w, zero halo
  __shared__ float rs[4], rq[4];
  const int tid = threadIdx.x;
  const int ht = blockIdx.x & 31;
  const int bc = blockIdx.x >> 5;
  const int c = bc % CCH;
  float sc, sh; get_ss_wave(c, tid&63, pstat, pgam, pbet, sc, sh);
  const float w0=wgt[c*5+0], w1=wgt[c*5+1], w2=wgt[c*5+2], w3=wgt[c*5+3], w4=wgt[c*5+4];
  const size_t base = (size_t)bc*HWSZ + (size_t)ht*(8*WCOL);

  if (tid < 64){
    int r = tid>>3, k = tid&7;
    xs[r*264 + (k<4 ? k : 256+k)] = 0.f;
  }
  const int r = tid >> 5, m = tid & 31;
  {
    uint4 v = *(const uint4*)(in + base + (size_t)r*WCOL + m*8);
    u32 rr[4] = {v.x, v.y, v.z, v.w};
    float f[8];
    #pragma unroll
    for (int q=0;q<4;++q){
      f[2*q]   = clip8(h2f((u16)rr[q])*sc + sh);
      f[2*q+1] = clip8(h2f((u16)(rr[q]>>16))*sc + sh);
    }
    float4* dst = (float4*)&xs[r*264 + 4 + m*8];
    dst[0] = make_float4(f[0],f[1],f[2],f[3]);
    dst[1] = make_float4(f[4],f[5],f[6],f[7]);
  }
  __syncthreads();
  float lsum=0.f, lssq=0.f;
  {
    const float* row = &xs[r*264 + m*8];
    float4 a0 = *(const float4*)(row+0);
    float4 a1 = *(const float4*)(row+4);
    float4 a2 = *(const float4*)(row+8);
    float4 a3 = *(const float4*)(row+12);
    float v[16] = {a0.x,a0.y,a0.z,a0.w, a1.x,a1.y,a1.z,a1.w,
                   a2.x,a2.y,a2.z,a2.w, a3.x,a3.y,a3.z,a3.w};
    float o[8];
    #pragma unroll
    for (int j=0;j<8;++j){
      float y = w0*v[j+2];
      y = fmaf(w1, v[j+3], y);
      y = fmaf(w2, v[j+4], y);
      y = fmaf(w3, v[j+5], y);
      y = fmaf(w4, v[j+6], y);
      o[j] = y;
      lsum += y; lssq = fmaf(y,y,lssq);
    }
    *(uint4*)(out + base + (size_t)r*WCOL + m*8) =
        make_uint4(pack2(o[0],o[1]), pack2(o[2],o[3]), pack2(o[4],o[5]), pack2(o[6],o[7]));
  }
  #pragma unroll
  for (int off=32; off; off>>=1){ lsum += __shfl_xor(lsum,off); lssq += __shfl_xor(lssq,off); }
  if ((tid&63)==0){ rs[tid>>6]=lsum; rq[tid>>6]=lssq; }
  __syncthreads();
  if (tid==0){
    float* oshard = ostat + (size_t)(blockIdx.x & (NSH-1))*SST;
    atomicAdd(oshard + c,      rs[0]+rs[1]+rs[2]+rs[3]);
    atomicAdd(oshard + 72 + c, rq[0]+rq[1]+rq[2]+rq[3]);
  }
}

// ---------------- Final: out = h1 + relu(BN(y12)) (fp32 output) ----------------
__global__ __launch_bounds__(256) void k_final(const u16* __restrict__ y12, const u16* __restrict__ h1,
    float* __restrict__ outp,
    const float* __restrict__ pstat,
    const float* __restrict__ pgam, const float* __restrict__ pbet)
{
  __shared__ float tsc[CCH], tsh[CCH];
  if (threadIdx.x < CCH){
    int cc = threadIdx.x;
    float s=0.f, q=0.f;
    for (int sh2=0; sh2<NSH; ++sh2){ s += pstat[sh2*SST + cc]; q += pstat[sh2*SST + 72 + cc]; }
    float mean = s * (1.0f/(float)NPC);
    float var  = q * (1.0f/(float)NPC) - mean*mean;
    float scv = pgam[cc] * rsqrtf(var + BNEPS);
    tsc[cc] = scv;
    tsh[cc] = pbet[cc] - mean*scv;
  }
  __syncthreads();
  const size_t TOTALQ = (size_t)BBATCH*CCH*HWSZ/4;
  for (size_t q = (size_t)blockIdx.x*blockDim.x + threadIdx.x; q < TOTALQ;
       q += (size_t)gridDim.x*blockDim.x){
    int cch = (int)((q >> 14) % CCH);
    float sc = tsc[cch], sh = tsh[cch];
    uint2 a = *(const uint2*)(y12 + q*4);
    uint2 b = *(const uint2*)(h1 + q*4);
    float4 o;
    o.x = fmaxf(h2f((u16)a.x)*sc+sh, 0.f)       + h2f((u16)b.x);
    o.y = fmaxf(h2f((u16)(a.x>>16))*sc+sh, 0.f) + h2f((u16)(b.x>>16));
    o.z = fmaxf(h2f((u16)a.y)*sc+sh, 0.f)       + h2f((u16)b.y);
    o.w = fmaxf(h2f((u16)(a.y>>16))*sc+sh, 0.f) + h2f((u16)(b.y>>16));
    *(float4*)(outp + q*4) = o;
  }
}

extern "C" void kernel_launch(void* const* d_in, const int* in_sizes, int n_in,
                              void* d_out, int out_size, void* d_ws, size_t ws_size,
                              hipStream_t stream)
{
  (void)in_sizes; (void)n_in; (void)out_size;
  const float* x   = (const float*)d_in[0];
  const float* ew  = (const float*)d_in[1];
  const float* eg  = (const float*)d_in[3];
  const float* ebt = (const float*)d_in[4];
  const float* iw  = (const float*)d_in[5];
  const float* ig  = (const float*)d_in[6];
  const float* ibt = (const float*)d_in[7];
  const float* dwt = (const float*)d_in[8];
  const float* dg  = (const float*)d_in[10];
  const float* dbt = (const float*)d_in[11];
  const float* pw  = (const float*)d_in[12];
  const float* pg  = (const float*)d_in[14];
  const float* pbt = (const float*)d_in[15];
  float* outp = (float*)d_out;

  const size_t BUFE = (size_t)BBATCH*CCH*HWSZ;     // 18,874,368 elements
  const size_t BUFB = BUFE*2;                      // fp16: 37.75 MB per buffer
  const size_t STATSB = (size_t)13*NSH*SST*sizeof(float);  // ~479 KB
  char* ws = (char*)d_ws;
  u16* A = (u16*)ws;
  u16* H = (u16*)(ws + BUFB);                      // shared h0/h1 buffer
  u16* B;
  float* stats;
  if (ws_size >= 3*BUFB + STATSB + 256){
    B = (u16*)(ws + 2*BUFB);
    stats = (float*)(ws + 3*BUFB);
  } else {
    // B ping-pong buffer lives in d_out (dead before k_final, which reads A and H only)
    B = (u16*)d_out;
    stats = (float*)(ws + 2*BUFB);
  }
  #define ST(s) (stats + (size_t)(s)*NSH*SST)

  hipMemsetAsync(stats, 0, STATSB, stream);

  dim3 blk(256);
  dim3 blkpw(512);
  // s0: expand pointwise (fp32 x -> y0 in A), raw stats0
  k_pw<36,1><<<BBATCH*HROW, blkpw, 0, stream>>>((const void*)x, A, ew,
      nullptr, nullptr, nullptr, ST(0));
  // unit 0
  k_iir<1><<<BBATCH*CCH, blk, 0, stream>>>(A, B, iw+0,   H, ST(0), eg, ebt, ST(1));
  k_dw    <<<BBATCH*CCH*32, blk, 0, stream>>>(B, A, dwt+0,    ST(1), ig+0,   ibt+0,   ST(2));
  k_pw<72,0><<<BBATCH*HROW, blkpw, 0, stream>>>(A, B, pw+0,     ST(2), dg+0,   dbt+0,   ST(3));
  // unit 1
  k_iir<0><<<BBATCH*CCH, blk, 0, stream>>>(B, A, iw+216, nullptr, ST(3), pg+0,  pbt+0,  ST(4));
  k_dw    <<<BBATCH*CCH*32, blk, 0, stream>>>(A, B, dwt+360,  ST(4), ig+72,  ibt+72,  ST(5));
  k_pw<72,0><<<BBATCH*HROW, blkpw, 0, stream>>>(B, A, pw+5184,  ST(5), dg+72,  dbt+72,  ST(6));
  // unit 2 (residual: h1 = h0 + relu(BN(y6)); IIR on h1; h1 kept in H)
  k_iir<2><<<BBATCH*CCH, blk, 0, stream>>>(A, B, iw+432, H, ST(6), pg+72, pbt+72, ST(7));
  k_dw    <<<BBATCH*CCH*32, blk, 0, stream>>>(B, A, dwt+720,  ST(7), ig+144, ibt+144, ST(8));
  k_pw<72,0><<<BBATCH*HROW, blkpw, 0, stream>>>(A, B, pw+10368, ST(8), dg+144, dbt+144, ST(9));
  // unit 3
  k_iir<0><<<BBATCH*CCH, blk, 0, stream>>>(B, A, iw+648, nullptr, ST(9), pg+144, pbt+144, ST(10));
  k_dw    <<<BBATCH*CCH*32, blk, 0, stream>>>(A, B, dwt+1080, ST(10), ig+216, ibt+216, ST(11));
  k_pw<72,0><<<BBATCH*HROW, blkpw, 0, stream>>>(B, A, pw+15552, ST(11), dg+216, dbt+216, ST(12));
  // out = h1 + relu(BN(y12))
  k_final<<<2048, blk, 0, stream>>>(A, H, outp, ST(12), pg+216, pbt+216);
  #undef ST
}

// Round 9
// 377.344 us; speedup vs baseline: 6.6438x; 1.1984x over previous
//
#include <hip/hip_runtime.h>
#include <hip/hip_fp16.h>

#define BBATCH 4
#define CCH 72
#define HROW 256
#define WCOL 256
#define HWSZ (HROW*WCOL)
#define NPC (BBATCH*HROW*WCOL)
#define BNEPS 1e-3f
#define NSH 64        // stats shards (R5: fixes same-address atomic serialization)
#define SST 144       // floats per shard: [0..71]=sum, [72..143]=sumsq

typedef unsigned short u16;
typedef unsigned int u32;
typedef _Float16 h8 __attribute__((ext_vector_type(8)));
typedef float f32x4 __attribute__((ext_vector_type(4)));

__device__ __forceinline__ float h2f(u16 h_){ return __half2float(__ushort_as_half(h_)); }
__device__ __forceinline__ u16 f2h(float f){ return __half_as_ushort(__float2half(f)); }
__device__ __forceinline__ u32 pack2(float a, float b){ return (u32)f2h(a) | ((u32)f2h(b)<<16); }
__device__ __forceinline__ float clip8(float v){ return fminf(fmaxf(v,-8.f),8.f); }

// BN-train scale/shift from sharded sum/sumsq (wave-parallel butterfly). c wave-uniform.
__device__ __forceinline__ void get_ss_wave(int c, int lane, const float* __restrict__ pstat,
                                            const float* __restrict__ gam, const float* __restrict__ bet,
                                            float& sc, float& sh){
  float s = pstat[lane*SST + c];
  float q = pstat[lane*SST + 72 + c];
  #pragma unroll
  for (int off=32; off; off>>=1){ s += __shfl_xor(s,off); q += __shfl_xor(q,off); }
  float mean = s * (1.0f/(float)NPC);
  float var  = q * (1.0f/(float)NPC) - mean*mean;
  sc = gam[c] * rsqrtf(var + BNEPS);
  sh = bet[c] - mean*sc;
}

// ---------------- Pointwise conv (CIN -> 72) via MFMA 16x16x32_f16, one-shot staging ----------
// R8 post-mortem: 6-phase dbuf pipeline stalled on barrier vmcnt(0) drains each phase
// (MfmaUtil 5%, VALUBusy 32%). Now: stage ALL of X once (issued at kernel top, one latency
// exposure), then 30 MFMAs barrier-free. fp16 weights only (no hi/lo: +~3e-4/stage error,
// BN renormalizes). B-frag LDS px-stride 18 -> g-groups hit banks {0,8,16,24}: conflict-free.
// Epilogue: acc -> LDS [72][264] -> coalesced uint4 stores with fused stats readback.
template<int CIN, int RAW>
__global__ __launch_bounds__(512) void k_pw(const void* __restrict__ in_,
    u16* __restrict__ out, const float* __restrict__ wgt,
    const float* __restrict__ pstat,
    const float* __restrict__ pgam, const float* __restrict__ pbet,
    float* __restrict__ ostat)
{
  constexpr int KB   = (CIN + 31) / 32;  // K-steps of 32
  constexpr int CPAD = KB * 32;
  constexpr int CST  = CPAD + 1;         // +1 c-row: pxtile stride -> bank offset 9 (spread)
  constexpr int XST  = 18;               // px stride (u16): g-groups 288B apart -> bank+8
  constexpr int XSZ  = 16 * CST * XST;
  constexpr int ESZ  = 72 * 264;
  constexpr int SSZ  = (XSZ > ESZ) ? XSZ : ESZ;
  constexpr int NXT  = (CIN*32 + 511) / 512;

  __shared__ u16 W[KB][80][40];          // fp16 weights [kb][out-ch(pad80)][k(pad40,16B rows)]
  __shared__ u16 xs[SSZ];                // X tile [pxt][c][18]; reused as epilogue [72][264]
  __shared__ float tsc[80], tsh[80];
  __shared__ float ps2[80], pq2[80];
  __shared__ float sst[72], sqt[72];

  const int tid  = threadIdx.x;
  const int lane = tid & 63;
  const int wid  = tid >> 6;             // wave 0..7 -> pxtiles {2wid, 2wid+1}
  const int g    = lane >> 4;            // k-octet group
  const int li   = lane & 15;
  const int b    = blockIdx.x >> 8;
  const int hrow = blockIdx.x & 255;

  // ---- issue X global loads immediately (latency overlaps all prologue work) ----
  uint4  xr[NXT];
  float4 xa[NXT], xb[NXT];
  #pragma unroll
  for (int it = 0; it < NXT; ++it){
    int e = tid + it*512;
    if (e < CIN*32){
      int c = e >> 5, o8 = e & 31;
      if constexpr (RAW){
        const float* ip = (const float*)in_ + (size_t)b*CIN*HWSZ + (size_t)c*HWSZ + (size_t)hrow*WCOL + o8*8;
        xa[it] = *(const float4*)ip;
        xb[it] = *(const float4*)(ip+4);
      } else {
        const u16* ip = (const u16*)in_ + (size_t)b*CIN*HWSZ + (size_t)c*HWSZ + (size_t)hrow*WCOL + o8*8;
        xr[it] = *(const uint4*)ip;
      }
    }
  }

  if (tid < 80){ ps2[tid] = 0.f; pq2[tid] = 0.f; }
  if (tid < 72){ sst[tid] = 0.f; sqt[tid] = 0.f; }

  // ---- zero-fill K-pad channels of xs ----
  for (int e = tid; e < (CPAD-CIN)*32; e += 512){
    int c = CIN + (e >> 5), o8 = e & 31;
    int pxt = o8 >> 1, pp = (o8 & 1) * 8;
    *(uint4*)&xs[(pxt*CST + c)*XST + pp] = make_uint4(0,0,0,0);
  }

  // ---- stage W fp16 (zero-padded) ----
  for (int e = tid; e < KB*80*40; e += 512){
    int kb  = e / 3200;
    int rem = e - kb*3200;
    int row = rem / 40;
    int col = rem - row*40;
    int c   = kb*32 + col;
    float w = 0.f;
    if (row < 72 && col < 32 && c < CIN) w = wgt[row*CIN + c];
    W[kb][row][col] = f2h(w);
  }

  // ---- BN scale/shift of the input (4-way-parallel shard sum) ----
  if constexpr (!RAW){
    if ((tid & 127) < 72){
      int c = tid & 127, sg = tid >> 7;
      float s = 0.f, q = 0.f;
      #pragma unroll
      for (int k2 = 0; k2 < 16; ++k2){
        s += pstat[(sg*16 + k2)*SST + c];
        q += pstat[(sg*16 + k2)*SST + 72 + c];
      }
      atomicAdd(&ps2[c], s); atomicAdd(&pq2[c], q);
    }
    __syncthreads();
    if (tid < CIN){
      float mean = ps2[tid] * (1.0f/(float)NPC);
      float var  = pq2[tid] * (1.0f/(float)NPC) - mean*mean;
      float scv  = pgam[tid] * rsqrtf(var + BNEPS);
      tsc[tid] = scv;
      tsh[tid] = pbet[tid] - mean*scv;
    }
  }
  __syncthreads();

  // ---- transform + write X tile ----
  #pragma unroll
  for (int it = 0; it < NXT; ++it){
    int e = tid + it*512;
    if (e < CIN*32){
      int c = e >> 5, o8 = e & 31;
      int pxt = o8 >> 1, pp = (o8 & 1) * 8;
      float v[8];
      if constexpr (RAW){
        v[0]=xa[it].x; v[1]=xa[it].y; v[2]=xa[it].z; v[3]=xa[it].w;
        v[4]=xb[it].x; v[5]=xb[it].y; v[6]=xb[it].z; v[7]=xb[it].w;
      } else {
        u32 rr[4] = {xr[it].x, xr[it].y, xr[it].z, xr[it].w};
        float scv = tsc[c], shv = tsh[c];
        #pragma unroll
        for (int q2=0; q2<4; ++q2){
          v[2*q2]   = clip8(h2f((u16)rr[q2])*scv + shv);
          v[2*q2+1] = clip8(h2f((u16)(rr[q2]>>16))*scv + shv);
        }
      }
      uint4 pk;
      pk.x = pack2(v[0],v[1]); pk.y = pack2(v[2],v[3]);
      pk.z = pack2(v[4],v[5]); pk.w = pack2(v[6],v[7]);
      *(uint4*)&xs[(pxt*CST + c)*XST + pp] = pk;
    }
  }
  __syncthreads();

  // ---- MFMA: barrier-free K/N loop (A row=li, k-oct=g verified R8; D col=li,row=g*4+r m89) ----
  f32x4 acc[5][2];
  #pragma unroll
  for (int mt=0; mt<5; ++mt){ acc[mt][0] = (f32x4){0,0,0,0}; acc[mt][1] = (f32x4){0,0,0,0}; }
  const int pxA = wid*2, pxB = wid*2 + 1;
  #pragma unroll
  for (int kb = 0; kb < KB; ++kb){
    h8 bf0, bf1;
    #pragma unroll
    for (int j = 0; j < 8; ++j){
      bf0[j] = *(const _Float16*)&xs[(pxA*CST + kb*32 + g*8 + j)*XST + li];
      bf1[j] = *(const _Float16*)&xs[(pxB*CST + kb*32 + g*8 + j)*XST + li];
    }
    #pragma unroll
    for (int mt = 0; mt < 5; ++mt){
      h8 ah = *(const h8*)&W[kb][mt*16 + li][g*8];
      acc[mt][0] = __builtin_amdgcn_mfma_f32_16x16x32_f16(ah, bf0, acc[mt][0], 0, 0, 0);
      acc[mt][1] = __builtin_amdgcn_mfma_f32_16x16x32_f16(ah, bf1, acc[mt][1], 0, 0, 0);
    }
  }
  __syncthreads();   // xs reads complete -> reuse as epilogue tile

  // ---- epilogue: acc -> LDS [72][264] (2-way write conflicts only) ----
  #pragma unroll
  for (int mt = 0; mt < 5; ++mt){
    int o = mt*16 + g*4;
    if (o < 72){
      #pragma unroll
      for (int t2 = 0; t2 < 2; ++t2){
        int px = (wid*2 + t2)*16 + li;
        #pragma unroll
        for (int r = 0; r < 4; ++r)
          xs[(o + r)*264 + px] = f2h(acc[mt][t2][r]);
      }
    }
  }
  __syncthreads();

  // ---- readback: coalesced uint4 stores + fused stats ----
  #pragma unroll
  for (int it = 0; it < 5; ++it){
    int e = tid + it*512;
    if (e < 72*32){
      int o = e >> 5, m = e & 31;
      uint4 v = *(const uint4*)&xs[o*264 + m*8];
      u32 rr[4] = {v.x, v.y, v.z, v.w};
      float s = 0.f, q = 0.f;
      #pragma unroll
      for (int q2=0; q2<4; ++q2){
        float a  = h2f((u16)rr[q2]);
        float bq = h2f((u16)(rr[q2]>>16));
        s += a + bq;
        q = fmaf(a,a,q); q = fmaf(bq,bq,q);
      }
      *(uint4*)(out + (size_t)b*CCH*HWSZ + (size_t)o*HWSZ + (size_t)hrow*WCOL + m*8) = v;
      #pragma unroll
      for (int off = 1; off <= 16; off <<= 1){ s += __shfl_xor(s, off); q += __shfl_xor(q, off); }
      if ((lane & 31) == 0){ atomicAdd(&sst[o], s); atomicAdd(&sqt[o], q); }
    }
  }
  __syncthreads();
  if (tid < 72){
    float* oshard = ostat + (size_t)(blockIdx.x & (NSH-1))*SST;
    atomicAdd(oshard + tid,      sst[tid]);
    atomicAdd(oshard + 72 + tid, sqt[tid]);
  }
}

// ---------------- IIR scan along H, fused input BN+ReLU (+optional residual), fp16 IO ----
template<int MODE>
__global__ __launch_bounds__(256) void k_iir(const u16* __restrict__ in, u16* __restrict__ out,
    const float* __restrict__ wabc, u16* __restrict__ hbuf,
    const float* __restrict__ pstat,
    const float* __restrict__ pgam, const float* __restrict__ pbet,
    float* __restrict__ ostat)
{
  const int tid = threadIdx.x;
  const int bc = blockIdx.x;          // b*CCH + c
  const int c = bc % CCH;
  float sc, sh; get_ss_wave(c, tid&63, pstat, pgam, pbet, sc, sh);
  const float ka = wabc[c], kb = wabc[CCH+c], kcc = wabc[2*CCH+c];
  const size_t base = (size_t)bc*HWSZ + tid;
  float xprev=0.f, yprev=0.f, lsum=0.f, lssq=0.f;

  for (int hb = 0; hb < HROW; hb += 16){
    float x[16];
    #pragma unroll
    for (int j=0;j<16;++j){
      size_t idx = base + (size_t)(hb+j)*WCOL;
      float v = fmaxf(h2f(in[idx])*sc + sh, 0.f);
      if (MODE==1) hbuf[idx] = f2h(v);
      if (MODE==2){ v += h2f(hbuf[idx]); hbuf[idx] = f2h(v); }
      x[j] = v;
    }
    if (hb == 0){ xprev = x[0]; yprev = x[0]; }  // y0 = (a+b+c)*x0
    float t[16];
    t[0] = fmaf(ka, x[0], kb*xprev);
    #pragma unroll
    for (int j=1;j<16;++j) t[j] = fmaf(ka, x[j], kb*x[j-1]);
    #pragma unroll
    for (int j=0;j<16;++j){
      yprev = fmaf(kcc, yprev, t[j]);       // 1-FMA dependent chain
      out[base + (size_t)(hb+j)*WCOL] = f2h(yprev);
      lsum += yprev; lssq = fmaf(yprev,yprev,lssq);
    }
    xprev = x[15];
  }

  #pragma unroll
  for (int off=32; off; off>>=1){ lsum += __shfl_xor(lsum,off); lssq += __shfl_xor(lssq,off); }
  __shared__ float rs[4], rq[4];
  if ((tid&63)==0){ rs[tid>>6]=lsum; rq[tid>>6]=lssq; }
  __syncthreads();
  if (tid==0){
    float* oshard = ostat + (size_t)(blockIdx.x & (NSH-1))*SST;
    atomicAdd(oshard + c,      rs[0]+rs[1]+rs[2]+rs[3]);
    atomicAdd(oshard + 72 + c, rq[0]+rq[1]+rq[2]+rq[3]);
  }
}

// ---------------- Depthwise 5-tap along W, fused input BN+clip, fp16 IO ----------
__global__ __launch_bounds__(256) void k_dw(const u16* __restrict__ in, u16* __restrict__ out,
    const float* __restrict__ wgt,
    const float* __restrict__ pstat,
    const float* __restrict__ pgam, const float* __restrict__ pbet,
    float* __restrict__ ostat)
{
  __shared__ float xs[8*264];   // row stride 264, data at col 4+w, zero halo
  __shared__ float rs[4], rq[4];
  const int tid = threadIdx.x;
  const int ht = blockIdx.x & 31;
  const int bc = blockIdx.x >> 5;
  const int c = bc % CCH;
  float sc, sh; get_ss_wave(c, tid&63, pstat, pgam, pbet, sc, sh);
  const float w0=wgt[c*5+0], w1=wgt[c*5+1], w2=wgt[c*5+2], w3=wgt[c*5+3], w4=wgt[c*5+4];
  const size_t base = (size_t)bc*HWSZ + (size_t)ht*(8*WCOL);

  if (tid < 64){
    int r = tid>>3, k = tid&7;
    xs[r*264 + (k<4 ? k : 256+k)] = 0.f;
  }
  const int r = tid >> 5, m = tid & 31;
  {
    uint4 v = *(const uint4*)(in + base + (size_t)r*WCOL + m*8);
    u32 rr[4] = {v.x, v.y, v.z, v.w};
    float f[8];
    #pragma unroll
    for (int q=0;q<4;++q){
      f[2*q]   = clip8(h2f((u16)rr[q])*sc + sh);
      f[2*q+1] = clip8(h2f((u16)(rr[q]>>16))*sc + sh);
    }
    float4* dst = (float4*)&xs[r*264 + 4 + m*8];
    dst[0] = make_float4(f[0],f[1],f[2],f[3]);
    dst[1] = make_float4(f[4],f[5],f[6],f[7]);
  }
  __syncthreads();
  float lsum=0.f, lssq=0.f;
  {
    const float* row = &xs[r*264 + m*8];
    float4 a0 = *(const float4*)(row+0);
    float4 a1 = *(const float4*)(row+4);
    float4 a2 = *(const float4*)(row+8);
    float4 a3 = *(const float4*)(row+12);
    float v[16] = {a0.x,a0.y,a0.z,a0.w, a1.x,a1.y,a1.z,a1.w,
                   a2.x,a2.y,a2.z,a2.w, a3.x,a3.y,a3.z,a3.w};
    float o[8];
    #pragma unroll
    for (int j=0;j<8;++j){
      float y = w0*v[j+2];
      y = fmaf(w1, v[j+3], y);
      y = fmaf(w2, v[j+4], y);
      y = fmaf(w3, v[j+5], y);
      y = fmaf(w4, v[j+6], y);
      o[j] = y;
      lsum += y; lssq = fmaf(y,y,lssq);
    }
    *(uint4*)(out + base + (size_t)r*WCOL + m*8) =
        make_uint4(pack2(o[0],o[1]), pack2(o[2],o[3]), pack2(o[4],o[5]), pack2(o[6],o[7]));
  }
  #pragma unroll
  for (int off=32; off; off>>=1){ lsum += __shfl_xor(lsum,off); lssq += __shfl_xor(lssq,off); }
  if ((tid&63)==0){ rs[tid>>6]=lsum; rq[tid>>6]=lssq; }
  __syncthreads();
  if (tid==0){
    float* oshard = ostat + (size_t)(blockIdx.x & (NSH-1))*SST;
    atomicAdd(oshard + c,      rs[0]+rs[1]+rs[2]+rs[3]);
    atomicAdd(oshard + 72 + c, rq[0]+rq[1]+rq[2]+rq[3]);
  }
}

// ---------------- Final: out = h1 + relu(BN(y12)) (fp32 output) ----------------
__global__ __launch_bounds__(256) void k_final(const u16* __restrict__ y12, const u16* __restrict__ h1,
    float* __restrict__ outp,
    const float* __restrict__ pstat,
    const float* __restrict__ pgam, const float* __restrict__ pbet)
{
  __shared__ float tsc[CCH], tsh[CCH];
  if (threadIdx.x < CCH){
    int cc = threadIdx.x;
    float s=0.f, q=0.f;
    for (int sh2=0; sh2<NSH; ++sh2){ s += pstat[sh2*SST + cc]; q += pstat[sh2*SST + 72 + cc]; }
    float mean = s * (1.0f/(float)NPC);
    float var  = q * (1.0f/(float)NPC) - mean*mean;
    float scv = pgam[cc] * rsqrtf(var + BNEPS);
    tsc[cc] = scv;
    tsh[cc] = pbet[cc] - mean*scv;
  }
  __syncthreads();
  const size_t TOTALQ = (size_t)BBATCH*CCH*HWSZ/4;
  for (size_t q = (size_t)blockIdx.x*blockDim.x + threadIdx.x; q < TOTALQ;
       q += (size_t)gridDim.x*blockDim.x){
    int cch = (int)((q >> 14) % CCH);
    float sc = tsc[cch], sh = tsh[cch];
    uint2 a = *(const uint2*)(y12 + q*4);
    uint2 b = *(const uint2*)(h1 + q*4);
    float4 o;
    o.x = fmaxf(h2f((u16)a.x)*sc+sh, 0.f)       + h2f((u16)b.x);
    o.y = fmaxf(h2f((u16)(a.x>>16))*sc+sh, 0.f) + h2f((u16)(b.x>>16));
    o.z = fmaxf(h2f((u16)a.y)*sc+sh, 0.f)       + h2f((u16)b.y);
    o.w = fmaxf(h2f((u16)(a.y>>16))*sc+sh, 0.f) + h2f((u16)(b.y>>16));
    *(float4*)(outp + q*4) = o;
  }
}

extern "C" void kernel_launch(void* const* d_in, const int* in_sizes, int n_in,
                              void* d_out, int out_size, void* d_ws, size_t ws_size,
                              hipStream_t stream)
{
  (void)in_sizes; (void)n_in; (void)out_size;
  const float* x   = (const float*)d_in[0];
  const float* ew  = (const float*)d_in[1];
  const float* eg  = (const float*)d_in[3];
  const float* ebt = (const float*)d_in[4];
  const float* iw  = (const float*)d_in[5];
  const float* ig  = (const float*)d_in[6];
  const float* ibt = (const float*)d_in[7];
  const float* dwt = (const float*)d_in[8];
  const float* dg  = (const float*)d_in[10];
  const float* dbt = (const float*)d_in[11];
  const float* pw  = (const float*)d_in[12];
  const float* pg  = (const float*)d_in[14];
  const float* pbt = (const float*)d_in[15];
  float* outp = (float*)d_out;

  const size_t BUFE = (size_t)BBATCH*CCH*HWSZ;     // 18,874,368 elements
  const size_t BUFB = BUFE*2;                      // fp16: 37.75 MB per buffer
  const size_t STATSB = (size_t)13*NSH*SST*sizeof(float);  // ~479 KB
  char* ws = (char*)d_ws;
  u16* A = (u16*)ws;
  u16* H = (u16*)(ws + BUFB);                      // shared h0/h1 buffer
  u16* B;
  float* stats;
  if (ws_size >= 3*BUFB + STATSB + 256){
    B = (u16*)(ws + 2*BUFB);
    stats = (float*)(ws + 3*BUFB);
  } else {
    // B ping-pong buffer lives in d_out (dead before k_final, which reads A and H only)
    B = (u16*)d_out;
    stats = (float*)(ws + 2*BUFB);
  }
  #define ST(s) (stats + (size_t)(s)*NSH*SST)

  hipMemsetAsync(stats, 0, STATSB, stream);

  dim3 blk(256);
  dim3 blkpw(512);
  // s0: expand pointwise (fp32 x -> y0 in A), raw stats0
  k_pw<36,1><<<BBATCH*HROW, blkpw, 0, stream>>>((const void*)x, A, ew,
      nullptr, nullptr, nullptr, ST(0));
  // unit 0
  k_iir<1><<<BBATCH*CCH, blk, 0, stream>>>(A, B, iw+0,   H, ST(0), eg, ebt, ST(1));
  k_dw    <<<BBATCH*CCH*32, blk, 0, stream>>>(B, A, dwt+0,    ST(1), ig+0,   ibt+0,   ST(2));
  k_pw<72,0><<<BBATCH*HROW, blkpw, 0, stream>>>(A, B, pw+0,     ST(2), dg+0,   dbt+0,   ST(3));
  // unit 1
  k_iir<0><<<BBATCH*CCH, blk, 0, stream>>>(B, A, iw+216, nullptr, ST(3), pg+0,  pbt+0,  ST(4));
  k_dw    <<<BBATCH*CCH*32, blk, 0, stream>>>(A, B, dwt+360,  ST(4), ig+72,  ibt+72,  ST(5));
  k_pw<72,0><<<BBATCH*HROW, blkpw, 0, stream>>>(B, A, pw+5184,  ST(5), dg+72,  dbt+72,  ST(6));
  // unit 2 (residual: h1 = h0 + relu(BN(y6)); IIR on h1; h1 kept in H)
  k_iir<2><<<BBATCH*CCH, blk, 0, stream>>>(A, B, iw+432, H, ST(6), pg+72, pbt+72, ST(7));
  k_dw    <<<BBATCH*CCH*32, blk, 0, stream>>>(B, A, dwt+720,  ST(7), ig+144, ibt+144, ST(8));
  k_pw<72,0><<<BBATCH*HROW, blkpw, 0, stream>>>(A, B, pw+10368, ST(8), dg+144, dbt+144, ST(9));
  // unit 3
  k_iir<0><<<BBATCH*CCH, blk, 0, stream>>>(B, A, iw+648, nullptr, ST(9), pg+144, pbt+144, ST(10));
  k_dw    <<<BBATCH*CCH*32, blk, 0, stream>>>(A, B, dwt+1080, ST(10), ig+216, ibt+216, ST(11));
  k_pw<72,0><<<BBATCH*HROW, blkpw, 0, stream>>>(B, A, pw+15552, ST(11), dg+216, dbt+216, ST(12));
  // out = h1 + relu(BN(y12))
  k_final<<<2048, blk, 0, stream>>>(A, H, outp, ST(12), pg+216, pbt+216);
  #undef ST
}

// Round 10
// 339.196 us; speedup vs baseline: 7.3910x; 1.1125x over previous
//
#include <hip/hip_runtime.h>
#include <hip/hip_fp16.h>

#define BBATCH 4
#define CCH 72
#define HROW 256
#define WCOL 256
#define HWSZ (HROW*WCOL)
#define NPC (BBATCH*HROW*WCOL)
#define BNEPS 1e-3f
#define NSH 64        // stats shards (R5: fixes same-address atomic serialization)
#define SST 144       // floats per shard: [0..71]=sum, [72..143]=sumsq

typedef unsigned short u16;
typedef unsigned int u32;
typedef _Float16 h8 __attribute__((ext_vector_type(8)));
typedef float f32x4 __attribute__((ext_vector_type(4)));

__device__ __forceinline__ float h2f(u16 h_){ return __half2float(__ushort_as_half(h_)); }
__device__ __forceinline__ u16 f2h(float f){ return __half_as_ushort(__float2half(f)); }
__device__ __forceinline__ u32 pack2(float a, float b){ return (u32)f2h(a) | ((u32)f2h(b)<<16); }
__device__ __forceinline__ float clip8(float v){ return fminf(fmaxf(v,-8.f),8.f); }

// BN-train scale/shift from sharded sum/sumsq (wave-parallel butterfly). c wave-uniform.
__device__ __forceinline__ void get_ss_wave(int c, int lane, const float* __restrict__ pstat,
                                            const float* __restrict__ gam, const float* __restrict__ bet,
                                            float& sc, float& sh){
  float s = pstat[lane*SST + c];
  float q = pstat[lane*SST + 72 + c];
  #pragma unroll
  for (int off=32; off; off>>=1){ s += __shfl_xor(s,off); q += __shfl_xor(q,off); }
  float mean = s * (1.0f/(float)NPC);
  float var  = q * (1.0f/(float)NPC) - mean*mean;
  sc = gam[c] * rsqrtf(var + BNEPS);
  sh = bet[c] - mean*sc;
}

// ---------------- Weight prep: all pw weights -> padded fp16 [slab][80][40] ----------------
// slabs 0..1: expand (CIN=36, KB=2); slabs 2+3u..4+3u: unit u (CIN=72, KB=3). 14 slabs total.
__global__ __launch_bounds__(256) void k_prep(const float* __restrict__ ew,
    const float* __restrict__ pwall, u16* __restrict__ Wp)
{
  for (int e = blockIdx.x*256 + threadIdx.x; e < 14*3200; e += gridDim.x*256){
    int slab = e / 3200, rem = e - slab*3200;
    int row = rem / 40, col = rem - row*40;
    float w = 0.f;
    if (slab < 2){
      int c = slab*32 + col;
      if (row < 72 && col < 32 && c < 36) w = ew[row*36 + c];
    } else {
      int u = (slab-2)/3, kb = (slab-2)%3;
      int c = kb*32 + col;
      if (row < 72 && col < 32) w = pwall[u*5184 + row*72 + c];
    }
    Wp[e] = f2h(w);
  }
}

// ---------------- Pointwise conv (CIN -> 72) via MFMA 16x16x32_f16, one-shot staging ----------
// R9->R10: W no longer staged in LDS — A-fragments read straight from prepped global fp16
// (13.8KB, L1-resident, same addresses all waves -> broadcast). LDS 62->45KB => 3 blocks/CU.
// Shard-sum via 4 plain LDS slots + tree (no LDS atomics). Everything else as R9:
// one-shot X staging (loads issued at kernel top), barrier-free MFMA loop, LDS-bounce epilogue.
template<int CIN, int RAW>
__global__ __launch_bounds__(512) void k_pw(const void* __restrict__ in_,
    u16* __restrict__ out, const u16* __restrict__ Wp,
    const float* __restrict__ pstat,
    const float* __restrict__ pgam, const float* __restrict__ pbet,
    float* __restrict__ ostat)
{
  constexpr int KB   = (CIN + 31) / 32;  // K-steps of 32
  constexpr int CPAD = KB * 32;
  constexpr int CST  = CPAD + 1;         // +1 c-row so pxtile stride spreads banks
  constexpr int XST  = 18;               // px stride (u16): g-groups land on banks {0,8,16,24}
  constexpr int XSZ  = 16 * CST * XST;
  constexpr int ESZ  = 72 * 264;
  constexpr int SSZ  = (XSZ > ESZ) ? XSZ : ESZ;
  constexpr int NXT  = (CIN*32 + 511) / 512;

  __shared__ u16 xs[SSZ];                // X tile [pxt][c][18]; reused as epilogue [72][264]
  __shared__ float tsc[80], tsh[80];
  __shared__ float pp4[4][72], pq4[4][72];
  __shared__ float sst[72], sqt[72];

  const int tid  = threadIdx.x;
  const int lane = tid & 63;
  const int wid  = tid >> 6;             // wave 0..7 -> pxtiles {2wid, 2wid+1}
  const int g    = lane >> 4;            // k-octet group
  const int li   = lane & 15;
  const int b    = blockIdx.x >> 8;
  const int hrow = blockIdx.x & 255;

  // ---- issue X global loads immediately (latency overlaps all prologue work) ----
  uint4  xr[NXT];
  float4 xa[NXT], xb[NXT];
  #pragma unroll
  for (int it = 0; it < NXT; ++it){
    int e = tid + it*512;
    if (e < CIN*32){
      int c = e >> 5, o8 = e & 31;
      if constexpr (RAW){
        const float* ip = (const float*)in_ + (size_t)b*CIN*HWSZ + (size_t)c*HWSZ + (size_t)hrow*WCOL + o8*8;
        xa[it] = *(const float4*)ip;
        xb[it] = *(const float4*)(ip+4);
      } else {
        const u16* ip = (const u16*)in_ + (size_t)b*CIN*HWSZ + (size_t)c*HWSZ + (size_t)hrow*WCOL + o8*8;
        xr[it] = *(const uint4*)ip;
      }
    }
  }

  if (tid < 72){ sst[tid] = 0.f; sqt[tid] = 0.f; }

  // ---- zero-fill K-pad channels of xs ----
  for (int e = tid; e < (CPAD-CIN)*32; e += 512){
    int c = CIN + (e >> 5), o8 = e & 31;
    int pxt = o8 >> 1, pp = (o8 & 1) * 8;
    *(uint4*)&xs[(pxt*CST + c)*XST + pp] = make_uint4(0,0,0,0);
  }

  // ---- BN scale/shift of the input (4-group parallel shard sum, plain LDS writes) ----
  if constexpr (!RAW){
    int sg = tid >> 7, c = tid & 127;
    if (c < 72){
      float s = 0.f, q = 0.f;
      #pragma unroll
      for (int k2 = 0; k2 < 16; ++k2){
        s += pstat[(sg*16 + k2)*SST + c];
        q += pstat[(sg*16 + k2)*SST + 72 + c];
      }
      pp4[sg][c] = s; pq4[sg][c] = q;
    }
    __syncthreads();
    if (tid < CIN){
      float s = pp4[0][tid] + pp4[1][tid] + pp4[2][tid] + pp4[3][tid];
      float q = pq4[0][tid] + pq4[1][tid] + pq4[2][tid] + pq4[3][tid];
      float mean = s * (1.0f/(float)NPC);
      float var  = q * (1.0f/(float)NPC) - mean*mean;
      float scv  = pgam[tid] * rsqrtf(var + BNEPS);
      tsc[tid] = scv;
      tsh[tid] = pbet[tid] - mean*scv;
    }
  }
  __syncthreads();

  // ---- transform + write X tile ----
  #pragma unroll
  for (int it = 0; it < NXT; ++it){
    int e = tid + it*512;
    if (e < CIN*32){
      int c = e >> 5, o8 = e & 31;
      int pxt = o8 >> 1, pp = (o8 & 1) * 8;
      float v[8];
      if constexpr (RAW){
        v[0]=xa[it].x; v[1]=xa[it].y; v[2]=xa[it].z; v[3]=xa[it].w;
        v[4]=xb[it].x; v[5]=xb[it].y; v[6]=xb[it].z; v[7]=xb[it].w;
      } else {
        u32 rr[4] = {xr[it].x, xr[it].y, xr[it].z, xr[it].w};
        float scv = tsc[c], shv = tsh[c];
        #pragma unroll
        for (int q2=0; q2<4; ++q2){
          v[2*q2]   = clip8(h2f((u16)rr[q2])*scv + shv);
          v[2*q2+1] = clip8(h2f((u16)(rr[q2]>>16))*scv + shv);
        }
      }
      uint4 pk;
      pk.x = pack2(v[0],v[1]); pk.y = pack2(v[2],v[3]);
      pk.z = pack2(v[4],v[5]); pk.w = pack2(v[6],v[7]);
      *(uint4*)&xs[(pxt*CST + c)*XST + pp] = pk;
    }
  }
  __syncthreads();

  // ---- MFMA: barrier-free K/N loop. A from global (L1-hot), B from LDS. ----
  f32x4 acc[5][2];
  #pragma unroll
  for (int mt=0; mt<5; ++mt){ acc[mt][0] = (f32x4){0,0,0,0}; acc[mt][1] = (f32x4){0,0,0,0}; }
  const int pxA = wid*2, pxB = wid*2 + 1;
  #pragma unroll
  for (int kb = 0; kb < KB; ++kb){
    h8 bf0, bf1;
    #pragma unroll
    for (int j = 0; j < 8; ++j){
      bf0[j] = *(const _Float16*)&xs[(pxA*CST + kb*32 + g*8 + j)*XST + li];
      bf1[j] = *(const _Float16*)&xs[(pxB*CST + kb*32 + g*8 + j)*XST + li];
    }
    #pragma unroll
    for (int mt = 0; mt < 5; ++mt){
      h8 ah = *(const h8*)(Wp + (size_t)(kb*80 + mt*16 + li)*40 + g*8);
      acc[mt][0] = __builtin_amdgcn_mfma_f32_16x16x32_f16(ah, bf0, acc[mt][0], 0, 0, 0);
      acc[mt][1] = __builtin_amdgcn_mfma_f32_16x16x32_f16(ah, bf1, acc[mt][1], 0, 0, 0);
    }
  }
  __syncthreads();   // xs reads complete -> reuse as epilogue tile

  // ---- epilogue: acc -> LDS [72][264] ----
  #pragma unroll
  for (int mt = 0; mt < 5; ++mt){
    int o = mt*16 + g*4;
    if (o < 72){
      #pragma unroll
      for (int t2 = 0; t2 < 2; ++t2){
        int px = (wid*2 + t2)*16 + li;
        #pragma unroll
        for (int r = 0; r < 4; ++r)
          xs[(o + r)*264 + px] = f2h(acc[mt][t2][r]);
      }
    }
  }
  __syncthreads();

  // ---- readback: coalesced uint4 stores + fused stats ----
  #pragma unroll
  for (int it = 0; it < 5; ++it){
    int e = tid + it*512;
    if (e < 72*32){
      int o = e >> 5, m = e & 31;
      uint4 v = *(const uint4*)&xs[o*264 + m*8];
      u32 rr[4] = {v.x, v.y, v.z, v.w};
      float s = 0.f, q = 0.f;
      #pragma unroll
      for (int q2=0; q2<4; ++q2){
        float a  = h2f((u16)rr[q2]);
        float bq = h2f((u16)(rr[q2]>>16));
        s += a + bq;
        q = fmaf(a,a,q); q = fmaf(bq,bq,q);
      }
      *(uint4*)(out + (size_t)b*CCH*HWSZ + (size_t)o*HWSZ + (size_t)hrow*WCOL + m*8) = v;
      #pragma unroll
      for (int off = 1; off <= 16; off <<= 1){ s += __shfl_xor(s, off); q += __shfl_xor(q, off); }
      if ((lane & 31) == 0){ atomicAdd(&sst[o], s); atomicAdd(&sqt[o], q); }
    }
  }
  __syncthreads();
  if (tid < 72){
    float* oshard = ostat + (size_t)(blockIdx.x & (NSH-1))*SST;
    atomicAdd(oshard + tid,      sst[tid]);
    atomicAdd(oshard + 72 + tid, sqt[tid]);
  }
}

// ---------------- IIR scan along H, fused input BN+ReLU (+optional residual), fp16 IO ----
// R10: 2-deep load pipeline — chunk hb+16's loads issue before chunk hb's compute,
// hiding HBM latency under the dependent FMA chain (occupancy is ~1.1 blocks/CU).
template<int MODE>
__global__ __launch_bounds__(256) void k_iir(const u16* __restrict__ in, u16* __restrict__ out,
    const float* __restrict__ wabc, u16* __restrict__ hbuf,
    const float* __restrict__ pstat,
    const float* __restrict__ pgam, const float* __restrict__ pbet,
    float* __restrict__ ostat)
{
  const int tid = threadIdx.x;
  const int bc = blockIdx.x;          // b*CCH + c
  const int c = bc % CCH;
  float sc, sh; get_ss_wave(c, tid&63, pstat, pgam, pbet, sc, sh);
  const float ka = wabc[c], kb = wabc[CCH+c], kcc = wabc[2*CCH+c];
  const size_t base = (size_t)bc*HWSZ + tid;
  float xprev=0.f, yprev=0.f, lsum=0.f, lssq=0.f;

  float a0[16], a1[16], r0[16], r1[16];

  auto LOADC = [&](int hb, float* xv, float* rv){
    #pragma unroll
    for (int j=0;j<16;++j){
      size_t idx = base + (size_t)(hb+j)*WCOL;
      xv[j] = h2f(in[idx]);
      if (MODE==2) rv[j] = h2f(hbuf[idx]);
    }
  };
  auto COMPC = [&](int hb, const float* xv, const float* rv){
    float x[16];
    #pragma unroll
    for (int j=0;j<16;++j){
      float v = fmaxf(xv[j]*sc + sh, 0.f);
      if (MODE==1) hbuf[base + (size_t)(hb+j)*WCOL] = f2h(v);
      if (MODE==2){ v += rv[j]; hbuf[base + (size_t)(hb+j)*WCOL] = f2h(v); }
      x[j] = v;
    }
    if (hb == 0){ xprev = x[0]; yprev = x[0]; }  // y0 = (a+b+c)*x0
    float t[16];
    t[0] = fmaf(ka, x[0], kb*xprev);
    #pragma unroll
    for (int j=1;j<16;++j) t[j] = fmaf(ka, x[j], kb*x[j-1]);
    #pragma unroll
    for (int j=0;j<16;++j){
      yprev = fmaf(kcc, yprev, t[j]);       // 1-FMA dependent chain
      out[base + (size_t)(hb+j)*WCOL] = f2h(yprev);
      lsum += yprev; lssq = fmaf(yprev,yprev,lssq);
    }
    xprev = x[15];
  };

  LOADC(0, a0, r0);
  #pragma unroll
  for (int hb = 0; hb < HROW; hb += 32){
    LOADC(hb+16, a1, r1);
    COMPC(hb, a0, r0);
    if (hb+32 < HROW) LOADC(hb+32, a0, r0);
    COMPC(hb+16, a1, r1);
  }

  #pragma unroll
  for (int off=32; off; off>>=1){ lsum += __shfl_xor(lsum,off); lssq += __shfl_xor(lssq,off); }
  __shared__ float rs[4], rq[4];
  if ((tid&63)==0){ rs[tid>>6]=lsum; rq[tid>>6]=lssq; }
  __syncthreads();
  if (tid==0){
    float* oshard = ostat + (size_t)(blockIdx.x & (NSH-1))*SST;
    atomicAdd(oshard + c,      rs[0]+rs[1]+rs[2]+rs[3]);
    atomicAdd(oshard + 72 + c, rq[0]+rq[1]+rq[2]+rq[3]);
  }
}

// ---------------- Depthwise 5-tap along W, fused input BN+clip, fp16 IO ----------
__global__ __launch_bounds__(256) void k_dw(const u16* __restrict__ in, u16* __restrict__ out,
    const float* __restrict__ wgt,
    const float* __restrict__ pstat,
    const float* __restrict__ pgam, const float* __restrict__ pbet,
    float* __restrict__ ostat)
{
  __shared__ float xs[8*264];   // row stride 264, data at col 4+w, zero halo
  __shared__ float rs[4], rq[4];
  const int tid = threadIdx.x;
  const int ht = blockIdx.x & 31;
  const int bc = blockIdx.x >> 5;
  const int c = bc % CCH;
  float sc, sh; get_ss_wave(c, tid&63, pstat, pgam, pbet, sc, sh);
  const float w0=wgt[c*5+0], w1=wgt[c*5+1], w2=wgt[c*5+2], w3=wgt[c*5+3], w4=wgt[c*5+4];
  const size_t base = (size_t)bc*HWSZ + (size_t)ht*(8*WCOL);

  if (tid < 64){
    int r = tid>>3, k = tid&7;
    xs[r*264 + (k<4 ? k : 256+k)] = 0.f;
  }
  const int r = tid >> 5, m = tid & 31;
  {
    uint4 v = *(const uint4*)(in + base + (size_t)r*WCOL + m*8);
    u32 rr[4] = {v.x, v.y, v.z, v.w};
    float f[8];
    #pragma unroll
    for (int q=0;q<4;++q){
      f[2*q]   = clip8(h2f((u16)rr[q])*sc + sh);
      f[2*q+1] = clip8(h2f((u16)(rr[q]>>16))*sc + sh);
    }
    float4* dst = (float4*)&xs[r*264 + 4 + m*8];
    dst[0] = make_float4(f[0],f[1],f[2],f[3]);
    dst[1] = make_float4(f[4],f[5],f[6],f[7]);
  }
  __syncthreads();
  float lsum=0.f, lssq=0.f;
  {
    const float* row = &xs[r*264 + m*8];
    float4 a0 = *(const float4*)(row+0);
    float4 a1 = *(const float4*)(row+4);
    float4 a2 = *(const float4*)(row+8);
    float4 a3 = *(const float4*)(row+12);
    float v[16] = {a0.x,a0.y,a0.z,a0.w, a1.x,a1.y,a1.z,a1.w,
                   a2.x,a2.y,a2.z,a2.w, a3.x,a3.y,a3.z,a3.w};
    float o[8];
    #pragma unroll
    for (int j=0;j<8;++j){
      float y = w0*v[j+2];
      y = fmaf(w1, v[j+3], y);
      y = fmaf(w2, v[j+4], y);
      y = fmaf(w3, v[j+5], y);
      y = fmaf(w4, v[j+6], y);
      o[j] = y;
      lsum += y; lssq = fmaf(y,y,lssq);
    }
    *(uint4*)(out + base + (size_t)r*WCOL + m*8) =
        make_uint4(pack2(o[0],o[1]), pack2(o[2],o[3]), pack2(o[4],o[5]), pack2(o[6],o[7]));
  }
  #pragma unroll
  for (int off=32; off; off>>=1){ lsum += __shfl_xor(lsum,off); lssq += __shfl_xor(lssq,off); }
  if ((tid&63)==0){ rs[tid>>6]=lsum; rq[tid>>6]=lssq; }
  __syncthreads();
  if (tid==0){
    float* oshard = ostat + (size_t)(blockIdx.x & (NSH-1))*SST;
    atomicAdd(oshard + c,      rs[0]+rs[1]+rs[2]+rs[3]);
    atomicAdd(oshard + 72 + c, rq[0]+rq[1]+rq[2]+rq[3]);
  }
}

// ---------------- Final: out = h1 + relu(BN(y12)) (fp32 output) ----------------
__global__ __launch_bounds__(256) void k_final(const u16* __restrict__ y12, const u16* __restrict__ h1,
    float* __restrict__ outp,
    const float* __restrict__ pstat,
    const float* __restrict__ pgam, const float* __restrict__ pbet)
{
  __shared__ float tsc[CCH], tsh[CCH];
  if (threadIdx.x < CCH){
    int cc = threadIdx.x;
    float s=0.f, q=0.f;
    for (int sh2=0; sh2<NSH; ++sh2){ s += pstat[sh2*SST + cc]; q += pstat[sh2*SST + 72 + cc]; }
    float mean = s * (1.0f/(float)NPC);
    float var  = q * (1.0f/(float)NPC) - mean*mean;
    float scv = pgam[cc] * rsqrtf(var + BNEPS);
    tsc[cc] = scv;
    tsh[cc] = pbet[cc] - mean*scv;
  }
  __syncthreads();
  const size_t TOTALQ = (size_t)BBATCH*CCH*HWSZ/4;
  for (size_t q = (size_t)blockIdx.x*blockDim.x + threadIdx.x; q < TOTALQ;
       q += (size_t)gridDim.x*blockDim.x){
    int cch = (int)((q >> 14) % CCH);
    float sc = tsc[cch], sh = tsh[cch];
    uint2 a = *(const uint2*)(y12 + q*4);
    uint2 b = *(const uint2*)(h1 + q*4);
    float4 o;
    o.x = fmaxf(h2f((u16)a.x)*sc+sh, 0.f)       + h2f((u16)b.x);
    o.y = fmaxf(h2f((u16)(a.x>>16))*sc+sh, 0.f) + h2f((u16)(b.x>>16));
    o.z = fmaxf(h2f((u16)a.y)*sc+sh, 0.f)       + h2f((u16)b.y);
    o.w = fmaxf(h2f((u16)(a.y>>16))*sc+sh, 0.f) + h2f((u16)(b.y>>16));
    *(float4*)(outp + q*4) = o;
  }
}

extern "C" void kernel_launch(void* const* d_in, const int* in_sizes, int n_in,
                              void* d_out, int out_size, void* d_ws, size_t ws_size,
                              hipStream_t stream)
{
  (void)in_sizes; (void)n_in; (void)out_size;
  const float* x   = (const float*)d_in[0];
  const float* ew  = (const float*)d_in[1];
  const float* eg  = (const float*)d_in[3];
  const float* ebt = (const float*)d_in[4];
  const float* iw  = (const float*)d_in[5];
  const float* ig  = (const float*)d_in[6];
  const float* ibt = (const float*)d_in[7];
  const float* dwt = (const float*)d_in[8];
  const float* dg  = (const float*)d_in[10];
  const float* dbt = (const float*)d_in[11];
  const float* pw  = (const float*)d_in[12];
  const float* pg  = (const float*)d_in[14];
  const float* pbt = (const float*)d_in[15];
  float* outp = (float*)d_out;

  const size_t BUFE = (size_t)BBATCH*CCH*HWSZ;     // 18,874,368 elements
  const size_t BUFB = BUFE*2;                      // fp16: 37.75 MB per buffer
  const size_t STATSB = (size_t)13*NSH*SST*sizeof(float);  // ~479 KB
  const size_t WPB = (size_t)14*3200*sizeof(u16);  // 89.6 KB prepped weights
  char* ws = (char*)d_ws;
  u16* A = (u16*)ws;
  u16* H = (u16*)(ws + BUFB);                      // shared h0/h1 buffer
  u16* B;
  float* stats;
  if (ws_size >= 3*BUFB + STATSB + WPB + 256){
    B = (u16*)(ws + 2*BUFB);
    stats = (float*)(ws + 3*BUFB);
  } else {
    // B ping-pong buffer lives in d_out (dead before k_final, which reads A and H only)
    B = (u16*)d_out;
    stats = (float*)(ws + 2*BUFB);
  }
  u16* Wp = (u16*)((char*)stats + STATSB);
  #define ST(s) (stats + (size_t)(s)*NSH*SST)
  #define WSLAB(u) (Wp + (size_t)(2 + 3*(u))*3200)

  hipMemsetAsync(stats, 0, STATSB, stream);

  dim3 blk(256);
  dim3 blkpw(512);
  k_prep<<<18, blk, 0, stream>>>(ew, pw, Wp);
  // s0: expand pointwise (fp32 x -> y0 in A), raw stats0
  k_pw<36,1><<<BBATCH*HROW, blkpw, 0, stream>>>((const void*)x, A, Wp,
      nullptr, nullptr, nullptr, ST(0));
  // unit 0
  k_iir<1><<<BBATCH*CCH, blk, 0, stream>>>(A, B, iw+0,   H, ST(0), eg, ebt, ST(1));
  k_dw    <<<BBATCH*CCH*32, blk, 0, stream>>>(B, A, dwt+0,    ST(1), ig+0,   ibt+0,   ST(2));
  k_pw<72,0><<<BBATCH*HROW, blkpw, 0, stream>>>(A, B, WSLAB(0), ST(2), dg+0,   dbt+0,   ST(3));
  // unit 1
  k_iir<0><<<BBATCH*CCH, blk, 0, stream>>>(B, A, iw+216, nullptr, ST(3), pg+0,  pbt+0,  ST(4));
  k_dw    <<<BBATCH*CCH*32, blk, 0, stream>>>(A, B, dwt+360,  ST(4), ig+72,  ibt+72,  ST(5));
  k_pw<72,0><<<BBATCH*HROW, blkpw, 0, stream>>>(B, A, WSLAB(1), ST(5), dg+72,  dbt+72,  ST(6));
  // unit 2 (residual: h1 = h0 + relu(BN(y6)); IIR on h1; h1 kept in H)
  k_iir<2><<<BBATCH*CCH, blk, 0, stream>>>(A, B, iw+432, H, ST(6), pg+72, pbt+72, ST(7));
  k_dw    <<<BBATCH*CCH*32, blk, 0, stream>>>(B, A, dwt+720,  ST(7), ig+144, ibt+144, ST(8));
  k_pw<72,0><<<BBATCH*HROW, blkpw, 0, stream>>>(A, B, WSLAB(2), ST(8), dg+144, dbt+144, ST(9));
  // unit 3
  k_iir<0><<<BBATCH*CCH, blk, 0, stream>>>(B, A, iw+648, nullptr, ST(9), pg+144, pbt+144, ST(10));
  k_dw    <<<BBATCH*CCH*32, blk, 0, stream>>>(A, B, dwt+1080, ST(10), ig+216, ibt+216, ST(11));
  k_pw<72,0><<<BBATCH*HROW, blkpw, 0, stream>>>(B, A, WSLAB(3), ST(11), dg+216, dbt+216, ST(12));
  // out = h1 + relu(BN(y12))
  k_final<<<2048, blk, 0, stream>>>(A, H, outp, ST(12), pg+216, pbt+216);
  #undef ST
  #undef WSLAB
}

// Round 11
// 334.179 us; speedup vs baseline: 7.5020x; 1.0150x over previous
//
#include <hip/hip_runtime.h>
#include <hip/hip_fp16.h>

#define BBATCH 4
#define CCH 72
#define HROW 256
#define WCOL 256
#define HWSZ (HROW*WCOL)
#define NPC (BBATCH*HROW*WCOL)
#define BNEPS 1e-3f
#define NSH 64        // stats shards (R5: fixes same-address atomic serialization)
#define SST 144       // floats per shard: [0..71]=sum, [72..143]=sumsq

typedef unsigned short u16;
typedef unsigned int u32;
typedef _Float16 h8 __attribute__((ext_vector_type(8)));
typedef float f32x4 __attribute__((ext_vector_type(4)));

__device__ __forceinline__ float h2f(u16 h_){ return __half2float(__ushort_as_half(h_)); }
__device__ __forceinline__ u16 f2h(float f){ return __half_as_ushort(__float2half(f)); }
__device__ __forceinline__ u32 pack2(float a, float b){ return (u32)f2h(a) | ((u32)f2h(b)<<16); }
__device__ __forceinline__ float clip8(float v){ return fminf(fmaxf(v,-8.f),8.f); }

// BN-train scale/shift from sharded sum/sumsq (wave-parallel butterfly). c wave-uniform.
__device__ __forceinline__ void get_ss_wave(int c, int lane, const float* __restrict__ pstat,
                                            const float* __restrict__ gam, const float* __restrict__ bet,
                                            float& sc, float& sh){
  float s = pstat[lane*SST + c];
  float q = pstat[lane*SST + 72 + c];
  #pragma unroll
  for (int off=32; off; off>>=1){ s += __shfl_xor(s,off); q += __shfl_xor(q,off); }
  float mean = s * (1.0f/(float)NPC);
  float var  = q * (1.0f/(float)NPC) - mean*mean;
  sc = gam[c] * rsqrtf(var + BNEPS);
  sh = bet[c] - mean*sc;
}

// ---------------- Weight prep: all pw weights -> padded fp16 [slab][80][40] ----------------
// slabs 0..1: expand (CIN=36, KB=2); slabs 2+3u..4+3u: unit u (CIN=72, KB=3). 14 slabs total.
__global__ __launch_bounds__(256) void k_prep(const float* __restrict__ ew,
    const float* __restrict__ pwall, u16* __restrict__ Wp)
{
  for (int e = blockIdx.x*256 + threadIdx.x; e < 14*3200; e += gridDim.x*256){
    int slab = e / 3200, rem = e - slab*3200;
    int row = rem / 40, col = rem - row*40;
    float w = 0.f;
    if (slab < 2){
      int c = slab*32 + col;
      if (row < 72 && col < 32 && c < 36) w = ew[row*36 + c];
    } else {
      int u = (slab-2)/3, kb = (slab-2)%3;
      int c = kb*32 + col;
      if (row < 72 && col < 32) w = pwall[u*5184 + row*72 + c];
    }
    Wp[e] = f2h(w);
  }
}

// ---------------- Pointwise conv (CIN -> 72) via MFMA 16x16x32_f16, zero-staging ----------
// R10->R11: X is NOT staged in LDS. Each lane reads its B-fragment elements straight from
// global (scalar u16; a wave's bf0+bf1 cover full 64B sectors), applies BN+clip in-register,
// and feeds the MFMA. Deletes the staging+transform passes and 2 barriers; LDS drops to the
// 38KB epilogue bounce (BN scratch overlaid on its head). A-fragments from prepped global
// weights (L1-broadcast, R10-proven). K-pad lanes clamped+zeroed in-register (NaN-safe).
template<int CIN, int RAW>
__global__ __launch_bounds__(512) void k_pw(const void* __restrict__ in_,
    u16* __restrict__ out, const u16* __restrict__ Wp,
    const float* __restrict__ pstat,
    const float* __restrict__ pgam, const float* __restrict__ pbet,
    float* __restrict__ ostat)
{
  constexpr int KB = (CIN + 31) / 32;    // K-steps of 32
  __shared__ __align__(16) u16 xs[72*264];   // epilogue bounce (38KB); head = BN scratch overlay
  __shared__ float tsc[80], tsh[80];
  __shared__ float sst[72], sqt[72];
  float* pp4 = (float*)xs;               // [4][80] shard partials (dead before epilogue)
  float* pq4 = pp4 + 320;

  const int tid  = threadIdx.x;
  const int lane = tid & 63;
  const int wid  = tid >> 6;             // wave 0..7 -> px columns wid*32 .. wid*32+31
  const int g    = lane >> 4;            // k-octet group
  const int li   = lane & 15;
  const int b    = blockIdx.x >> 8;
  const int hrow = blockIdx.x & 255;

  if (tid < 72){ sst[tid] = 0.f; sqt[tid] = 0.f; }

  // ---- BN scale/shift of the input (4-group parallel shard sum in overlaid LDS) ----
  if constexpr (!RAW){
    int sg = tid >> 7, c = tid & 127;
    if (c < 72){
      float s = 0.f, q = 0.f;
      #pragma unroll
      for (int k2 = 0; k2 < 16; ++k2){
        s += pstat[(sg*16 + k2)*SST + c];
        q += pstat[(sg*16 + k2)*SST + 72 + c];
      }
      pp4[sg*80 + c] = s; pq4[sg*80 + c] = q;
    }
    __syncthreads();
    if (tid < CIN){
      float s = pp4[tid] + pp4[80+tid] + pp4[160+tid] + pp4[240+tid];
      float q = pq4[tid] + pq4[80+tid] + pq4[160+tid] + pq4[240+tid];
      float mean = s * (1.0f/(float)NPC);
      float var  = q * (1.0f/(float)NPC) - mean*mean;
      float scv  = pgam[tid] * rsqrtf(var + BNEPS);
      tsc[tid] = scv;
      tsh[tid] = pbet[tid] - mean*scv;
    }
    __syncthreads();   // tsc/tsh ready; pp4/pq4 (xs head) now dead -> epilogue may reuse
  }

  // ---- MFMA loop: B-fragments direct from global, BN+clip in-register, no barriers ----
  const size_t base_in = (size_t)b*CIN*HWSZ + (size_t)hrow*WCOL;
  const int px0 = wid*32 + li;           // bf0 pixel; bf1 = px0+16 (same 64B line)
  f32x4 acc[5][2];
  #pragma unroll
  for (int mt=0; mt<5; ++mt){ acc[mt][0] = (f32x4){0,0,0,0}; acc[mt][1] = (f32x4){0,0,0,0}; }

  #pragma unroll
  for (int kb2 = 0; kb2 < KB; ++kb2){
    h8 bf0, bf1;
    #pragma unroll
    for (int j = 0; j < 8; ++j){
      int c  = kb2*32 + g*8 + j;
      int cc = (c < CIN) ? c : 0;        // clamp addr; value zeroed below (NaN-safe)
      float v0, v1;
      if constexpr (RAW){
        const float* ip = (const float*)in_ + base_in + (size_t)cc*HWSZ;
        v0 = ip[px0]; v1 = ip[px0 + 16];
      } else {
        const u16* ip = (const u16*)in_ + base_in + (size_t)cc*HWSZ;
        float scv = tsc[cc], shv = tsh[cc];
        v0 = clip8(h2f(ip[px0])*scv + shv);
        v1 = clip8(h2f(ip[px0 + 16])*scv + shv);
      }
      bool ok = (c < CIN);
      bf0[j] = (_Float16)(ok ? v0 : 0.f);
      bf1[j] = (_Float16)(ok ? v1 : 0.f);
    }
    #pragma unroll
    for (int mt = 0; mt < 5; ++mt){
      h8 ah = *(const h8*)(Wp + (size_t)(kb2*80 + mt*16 + li)*40 + g*8);
      acc[mt][0] = __builtin_amdgcn_mfma_f32_16x16x32_f16(ah, bf0, acc[mt][0], 0, 0, 0);
      acc[mt][1] = __builtin_amdgcn_mfma_f32_16x16x32_f16(ah, bf1, acc[mt][1], 0, 0, 0);
    }
  }

  // ---- epilogue: acc -> LDS [72][264] (waves write disjoint px columns) ----
  #pragma unroll
  for (int mt = 0; mt < 5; ++mt){
    int o = mt*16 + g*4;
    if (o < 72){
      #pragma unroll
      for (int t2 = 0; t2 < 2; ++t2){
        int px = wid*32 + t2*16 + li;
        #pragma unroll
        for (int r = 0; r < 4; ++r)
          xs[(o + r)*264 + px] = f2h(acc[mt][t2][r]);
      }
    }
  }
  __syncthreads();

  // ---- readback: coalesced uint4 stores + fused stats ----
  #pragma unroll
  for (int it = 0; it < 5; ++it){
    int e = tid + it*512;
    if (e < 72*32){
      int o = e >> 5, m = e & 31;
      uint4 v = *(const uint4*)&xs[o*264 + m*8];
      u32 rr[4] = {v.x, v.y, v.z, v.w};
      float s = 0.f, q = 0.f;
      #pragma unroll
      for (int q2=0; q2<4; ++q2){
        float a  = h2f((u16)rr[q2]);
        float bq = h2f((u16)(rr[q2]>>16));
        s += a + bq;
        q = fmaf(a,a,q); q = fmaf(bq,bq,q);
      }
      *(uint4*)(out + (size_t)b*CCH*HWSZ + (size_t)o*HWSZ + (size_t)hrow*WCOL + m*8) = v;
      #pragma unroll
      for (int off = 1; off <= 16; off <<= 1){ s += __shfl_xor(s, off); q += __shfl_xor(q, off); }
      if ((lane & 31) == 0){ atomicAdd(&sst[o], s); atomicAdd(&sqt[o], q); }
    }
  }
  __syncthreads();
  if (tid < 72){
    float* oshard = ostat + (size_t)(blockIdx.x & (NSH-1))*SST;
    atomicAdd(oshard + tid,      sst[tid]);
    atomicAdd(oshard + 72 + tid, sqt[tid]);
  }
}

// ---------------- IIR scan along H, fused input BN+ReLU (+optional residual), fp16 IO ----
// R10: 2-deep load pipeline — chunk hb+16's loads issue before chunk hb's compute.
template<int MODE>
__global__ __launch_bounds__(256) void k_iir(const u16* __restrict__ in, u16* __restrict__ out,
    const float* __restrict__ wabc, u16* __restrict__ hbuf,
    const float* __restrict__ pstat,
    const float* __restrict__ pgam, const float* __restrict__ pbet,
    float* __restrict__ ostat)
{
  const int tid = threadIdx.x;
  const int bc = blockIdx.x;          // b*CCH + c
  const int c = bc % CCH;
  float sc, sh; get_ss_wave(c, tid&63, pstat, pgam, pbet, sc, sh);
  const float ka = wabc[c], kb = wabc[CCH+c], kcc = wabc[2*CCH+c];
  const size_t base = (size_t)bc*HWSZ + tid;
  float xprev=0.f, yprev=0.f, lsum=0.f, lssq=0.f;

  float a0[16], a1[16], r0[16], r1[16];

  auto LOADC = [&](int hb, float* xv, float* rv){
    #pragma unroll
    for (int j=0;j<16;++j){
      size_t idx = base + (size_t)(hb+j)*WCOL;
      xv[j] = h2f(in[idx]);
      if (MODE==2) rv[j] = h2f(hbuf[idx]);
    }
  };
  auto COMPC = [&](int hb, const float* xv, const float* rv){
    float x[16];
    #pragma unroll
    for (int j=0;j<16;++j){
      float v = fmaxf(xv[j]*sc + sh, 0.f);
      if (MODE==1) hbuf[base + (size_t)(hb+j)*WCOL] = f2h(v);
      if (MODE==2){ v += rv[j]; hbuf[base + (size_t)(hb+j)*WCOL] = f2h(v); }
      x[j] = v;
    }
    if (hb == 0){ xprev = x[0]; yprev = x[0]; }  // y0 = (a+b+c)*x0
    float t[16];
    t[0] = fmaf(ka, x[0], kb*xprev);
    #pragma unroll
    for (int j=1;j<16;++j) t[j] = fmaf(ka, x[j], kb*x[j-1]);
    #pragma unroll
    for (int j=0;j<16;++j){
      yprev = fmaf(kcc, yprev, t[j]);       // 1-FMA dependent chain
      out[base + (size_t)(hb+j)*WCOL] = f2h(yprev);
      lsum += yprev; lssq = fmaf(yprev,yprev,lssq);
    }
    xprev = x[15];
  };

  LOADC(0, a0, r0);
  #pragma unroll
  for (int hb = 0; hb < HROW; hb += 32){
    LOADC(hb+16, a1, r1);
    COMPC(hb, a0, r0);
    if (hb+32 < HROW) LOADC(hb+32, a0, r0);
    COMPC(hb+16, a1, r1);
  }

  #pragma unroll
  for (int off=32; off; off>>=1){ lsum += __shfl_xor(lsum,off); lssq += __shfl_xor(lssq,off); }
  __shared__ float rs[4], rq[4];
  if ((tid&63)==0){ rs[tid>>6]=lsum; rq[tid>>6]=lssq; }
  __syncthreads();
  if (tid==0){
    float* oshard = ostat + (size_t)(blockIdx.x & (NSH-1))*SST;
    atomicAdd(oshard + c,      rs[0]+rs[1]+rs[2]+rs[3]);
    atomicAdd(oshard + 72 + c, rq[0]+rq[1]+rq[2]+rq[3]);
  }
}

// ---------------- Depthwise 5-tap along W, fused input BN+clip, fp16 IO ----------
__global__ __launch_bounds__(256) void k_dw(const u16* __restrict__ in, u16* __restrict__ out,
    const float* __restrict__ wgt,
    const float* __restrict__ pstat,
    const float* __restrict__ pgam, const float* __restrict__ pbet,
    float* __restrict__ ostat)
{
  __shared__ float xs[8*264];   // row stride 264, data at col 4+w, zero halo
  __shared__ float rs[4], rq[4];
  const int tid = threadIdx.x;
  const int ht = blockIdx.x & 31;
  const int bc = blockIdx.x >> 5;
  const int c = bc % CCH;
  float sc, sh; get_ss_wave(c, tid&63, pstat, pgam, pbet, sc, sh);
  const float w0=wgt[c*5+0], w1=wgt[c*5+1], w2=wgt[c*5+2], w3=wgt[c*5+3], w4=wgt[c*5+4];
  const size_t base = (size_t)bc*HWSZ + (size_t)ht*(8*WCOL);

  if (tid < 64){
    int r = tid>>3, k = tid&7;
    xs[r*264 + (k<4 ? k : 256+k)] = 0.f;
  }
  const int r = tid >> 5, m = tid & 31;
  {
    uint4 v = *(const uint4*)(in + base + (size_t)r*WCOL + m*8);
    u32 rr[4] = {v.x, v.y, v.z, v.w};
    float f[8];
    #pragma unroll
    for (int q=0;q<4;++q){
      f[2*q]   = clip8(h2f((u16)rr[q])*sc + sh);
      f[2*q+1] = clip8(h2f((u16)(rr[q]>>16))*sc + sh);
    }
    float4* dst = (float4*)&xs[r*264 + 4 + m*8];
    dst[0] = make_float4(f[0],f[1],f[2],f[3]);
    dst[1] = make_float4(f[4],f[5],f[6],f[7]);
  }
  __syncthreads();
  float lsum=0.f, lssq=0.f;
  {
    const float* row = &xs[r*264 + m*8];
    float4 a0 = *(const float4*)(row+0);
    float4 a1 = *(const float4*)(row+4);
    float4 a2 = *(const float4*)(row+8);
    float4 a3 = *(const float4*)(row+12);
    float v[16] = {a0.x,a0.y,a0.z,a0.w, a1.x,a1.y,a1.z,a1.w,
                   a2.x,a2.y,a2.z,a2.w, a3.x,a3.y,a3.z,a3.w};
    float o[8];
    #pragma unroll
    for (int j=0;j<8;++j){
      float y = w0*v[j+2];
      y = fmaf(w1, v[j+3], y);
      y = fmaf(w2, v[j+4], y);
      y = fmaf(w3, v[j+5], y);
      y = fmaf(w4, v[j+6], y);
      o[j] = y;
      lsum += y; lssq = fmaf(y,y,lssq);
    }
    *(uint4*)(out + base + (size_t)r*WCOL + m*8) =
        make_uint4(pack2(o[0],o[1]), pack2(o[2],o[3]), pack2(o[4],o[5]), pack2(o[6],o[7]));
  }
  #pragma unroll
  for (int off=32; off; off>>=1){ lsum += __shfl_xor(lsum,off); lssq += __shfl_xor(lssq,off); }
  if ((tid&63)==0){ rs[tid>>6]=lsum; rq[tid>>6]=lssq; }
  __syncthreads();
  if (tid==0){
    float* oshard = ostat + (size_t)(blockIdx.x & (NSH-1))*SST;
    atomicAdd(oshard + c,      rs[0]+rs[1]+rs[2]+rs[3]);
    atomicAdd(oshard + 72 + c, rq[0]+rq[1]+rq[2]+rq[3]);
  }
}

// ---------------- Final: out = h1 + relu(BN(y12)) (fp32 output) ----------------
__global__ __launch_bounds__(256) void k_final(const u16* __restrict__ y12, const u16* __restrict__ h1,
    float* __restrict__ outp,
    const float* __restrict__ pstat,
    const float* __restrict__ pgam, const float* __restrict__ pbet)
{
  __shared__ float tsc[CCH], tsh[CCH];
  if (threadIdx.x < CCH){
    int cc = threadIdx.x;
    float s=0.f, q=0.f;
    for (int sh2=0; sh2<NSH; ++sh2){ s += pstat[sh2*SST + cc]; q += pstat[sh2*SST + 72 + cc]; }
    float mean = s * (1.0f/(float)NPC);
    float var  = q * (1.0f/(float)NPC) - mean*mean;
    float scv = pgam[cc] * rsqrtf(var + BNEPS);
    tsc[cc] = scv;
    tsh[cc] = pbet[cc] - mean*scv;
  }
  __syncthreads();
  const size_t TOTALQ = (size_t)BBATCH*CCH*HWSZ/4;
  for (size_t q = (size_t)blockIdx.x*blockDim.x + threadIdx.x; q < TOTALQ;
       q += (size_t)gridDim.x*blockDim.x){
    int cch = (int)((q >> 14) % CCH);
    float sc = tsc[cch], sh = tsh[cch];
    uint2 a = *(const uint2*)(y12 + q*4);
    uint2 b = *(const uint2*)(h1 + q*4);
    float4 o;
    o.x = fmaxf(h2f((u16)a.x)*sc+sh, 0.f)       + h2f((u16)b.x);
    o.y = fmaxf(h2f((u16)(a.x>>16))*sc+sh, 0.f) + h2f((u16)(b.x>>16));
    o.z = fmaxf(h2f((u16)a.y)*sc+sh, 0.f)       + h2f((u16)b.y);
    o.w = fmaxf(h2f((u16)(a.y>>16))*sc+sh, 0.f) + h2f((u16)(b.y>>16));
    *(float4*)(outp + q*4) = o;
  }
}

extern "C" void kernel_launch(void* const* d_in, const int* in_sizes, int n_in,
                              void* d_out, int out_size, void* d_ws, size_t ws_size,
                              hipStream_t stream)
{
  (void)in_sizes; (void)n_in; (void)out_size;
  const float* x   = (const float*)d_in[0];
  const float* ew  = (const float*)d_in[1];
  const float* eg  = (const float*)d_in[3];
  const float* ebt = (const float*)d_in[4];
  const float* iw  = (const float*)d_in[5];
  const float* ig  = (const float*)d_in[6];
  const float* ibt = (const float*)d_in[7];
  const float* dwt = (const float*)d_in[8];
  const float* dg  = (const float*)d_in[10];
  const float* dbt = (const float*)d_in[11];
  const float* pw  = (const float*)d_in[12];
  const float* pg  = (const float*)d_in[14];
  const float* pbt = (const float*)d_in[15];
  float* outp = (float*)d_out;

  const size_t BUFE = (size_t)BBATCH*CCH*HWSZ;     // 18,874,368 elements
  const size_t BUFB = BUFE*2;                      // fp16: 37.75 MB per buffer
  const size_t STATSB = (size_t)13*NSH*SST*sizeof(float);  // ~479 KB
  const size_t WPB = (size_t)14*3200*sizeof(u16);  // 89.6 KB prepped weights
  char* ws = (char*)d_ws;
  u16* A = (u16*)ws;
  u16* H = (u16*)(ws + BUFB);                      // shared h0/h1 buffer
  u16* B;
  float* stats;
  if (ws_size >= 3*BUFB + STATSB + WPB + 256){
    B = (u16*)(ws + 2*BUFB);
    stats = (float*)(ws + 3*BUFB);
  } else {
    // B ping-pong buffer lives in d_out (dead before k_final, which reads A and H only)
    B = (u16*)d_out;
    stats = (float*)(ws + 2*BUFB);
  }
  u16* Wp = (u16*)((char*)stats + STATSB);
  #define ST(s) (stats + (size_t)(s)*NSH*SST)
  #define WSLAB(u) (Wp + (size_t)(2 + 3*(u))*3200)

  hipMemsetAsync(stats, 0, STATSB, stream);

  dim3 blk(256);
  dim3 blkpw(512);
  k_prep<<<18, blk, 0, stream>>>(ew, pw, Wp);
  // s0: expand pointwise (fp32 x -> y0 in A), raw stats0
  k_pw<36,1><<<BBATCH*HROW, blkpw, 0, stream>>>((const void*)x, A, Wp,
      nullptr, nullptr, nullptr, ST(0));
  // unit 0
  k_iir<1><<<BBATCH*CCH, blk, 0, stream>>>(A, B, iw+0,   H, ST(0), eg, ebt, ST(1));
  k_dw    <<<BBATCH*CCH*32, blk, 0, stream>>>(B, A, dwt+0,    ST(1), ig+0,   ibt+0,   ST(2));
  k_pw<72,0><<<BBATCH*HROW, blkpw, 0, stream>>>(A, B, WSLAB(0), ST(2), dg+0,   dbt+0,   ST(3));
  // unit 1
  k_iir<0><<<BBATCH*CCH, blk, 0, stream>>>(B, A, iw+216, nullptr, ST(3), pg+0,  pbt+0,  ST(4));
  k_dw    <<<BBATCH*CCH*32, blk, 0, stream>>>(A, B, dwt+360,  ST(4), ig+72,  ibt+72,  ST(5));
  k_pw<72,0><<<BBATCH*HROW, blkpw, 0, stream>>>(B, A, WSLAB(1), ST(5), dg+72,  dbt+72,  ST(6));
  // unit 2 (residual: h1 = h0 + relu(BN(y6)); IIR on h1; h1 kept in H)
  k_iir<2><<<BBATCH*CCH, blk, 0, stream>>>(A, B, iw+432, H, ST(6), pg+72, pbt+72, ST(7));
  k_dw    <<<BBATCH*CCH*32, blk, 0, stream>>>(B, A, dwt+720,  ST(7), ig+144, ibt+144, ST(8));
  k_pw<72,0><<<BBATCH*HROW, blkpw, 0, stream>>>(A, B, WSLAB(2), ST(8), dg+144, dbt+144, ST(9));
  // unit 3
  k_iir<0><<<BBATCH*CCH, blk, 0, stream>>>(B, A, iw+648, nullptr, ST(9), pg+144, pbt+144, ST(10));
  k_dw    <<<BBATCH*CCH*32, blk, 0, stream>>>(A, B, dwt+1080, ST(10), ig+216, ibt+216, ST(11));
  k_pw<72,0><<<BBATCH*HROW, blkpw, 0, stream>>>(B, A, WSLAB(3), ST(11), dg+216, dbt+216, ST(12));
  // out = h1 + relu(BN(y12))
  k_final<<<2048, blk, 0, stream>>>(A, H, outp, ST(12), pg+216, pbt+216);
  #undef ST
  #undef WSLAB
}

// Round 12
// 321.237 us; speedup vs baseline: 7.8042x; 1.0403x over previous
//
#include <hip/hip_runtime.h>
#include <hip/hip_fp16.h>

#define BBATCH 4
#define CCH 72
#define HROW 256
#define WCOL 256
#define HWSZ (HROW*WCOL)
#define NPC (BBATCH*HROW*WCOL)
#define BNEPS 1e-3f
#define NSH 64        // stats shards (R5: fixes same-address atomic serialization)
#define SST 144       // floats per shard: [0..71]=sum, [72..143]=sumsq

typedef unsigned short u16;
typedef unsigned int u32;
typedef _Float16 h8 __attribute__((ext_vector_type(8)));
typedef float f32x4 __attribute__((ext_vector_type(4)));

__device__ __forceinline__ float h2f(u16 h_){ return __half2float(__ushort_as_half(h_)); }
__device__ __forceinline__ u16 f2h(float f){ return __half_as_ushort(__float2half(f)); }
__device__ __forceinline__ u32 pack2(float a, float b){ return (u32)f2h(a) | ((u32)f2h(b)<<16); }
__device__ __forceinline__ float clip8(float v){ return fminf(fmaxf(v,-8.f),8.f); }

// BN-train scale/shift from sharded sum/sumsq (wave-parallel butterfly). c wave-uniform.
__device__ __forceinline__ void get_ss_wave(int c, int lane, const float* __restrict__ pstat,
                                            const float* __restrict__ gam, const float* __restrict__ bet,
                                            float& sc, float& sh){
  float s = pstat[lane*SST + c];
  float q = pstat[lane*SST + 72 + c];
  #pragma unroll
  for (int off=32; off; off>>=1){ s += __shfl_xor(s,off); q += __shfl_xor(q,off); }
  float mean = s * (1.0f/(float)NPC);
  float var  = q * (1.0f/(float)NPC) - mean*mean;
  sc = gam[c] * rsqrtf(var + BNEPS);
  sh = bet[c] - mean*sc;
}

// ---------------- Weight prep: all pw weights -> padded fp16 [slab][80][40] ----------------
// slabs 0..1: expand (CIN=36, KB=2); slabs 2+3u..4+3u: unit u (CIN=72, KB=3). 14 slabs total.
__global__ __launch_bounds__(256) void k_prep(const float* __restrict__ ew,
    const float* __restrict__ pwall, u16* __restrict__ Wp)
{
  for (int e = blockIdx.x*256 + threadIdx.x; e < 14*3200; e += gridDim.x*256){
    int slab = e / 3200, rem = e - slab*3200;
    int row = rem / 40, col = rem - row*40;
    float w = 0.f;
    if (slab < 2){
      int c = slab*32 + col;
      if (row < 72 && col < 32 && c < 36) w = ew[row*36 + c];
    } else {
      int u = (slab-2)/3, kb = (slab-2)%3;
      int c = kb*32 + col;
      if (row < 72 && col < 32) w = pwall[u*5184 + row*72 + c];
    }
    Wp[e] = f2h(w);
  }
}

// ---------------- Pointwise conv (CIN -> 72) via MFMA 16x16x32_f16, zero-staging (R11) ----------
template<int CIN, int RAW>
__global__ __launch_bounds__(512) void k_pw(const void* __restrict__ in_,
    u16* __restrict__ out, const u16* __restrict__ Wp,
    const float* __restrict__ pstat,
    const float* __restrict__ pgam, const float* __restrict__ pbet,
    float* __restrict__ ostat)
{
  constexpr int KB = (CIN + 31) / 32;    // K-steps of 32
  __shared__ __align__(16) u16 xs[72*264];   // epilogue bounce (38KB); head = BN scratch overlay
  __shared__ float tsc[80], tsh[80];
  __shared__ float sst[72], sqt[72];
  float* pp4 = (float*)xs;               // [4][80] shard partials (dead before epilogue)
  float* pq4 = pp4 + 320;

  const int tid  = threadIdx.x;
  const int lane = tid & 63;
  const int wid  = tid >> 6;             // wave 0..7 -> px columns wid*32 .. wid*32+31
  const int g    = lane >> 4;            // k-octet group
  const int li   = lane & 15;
  const int b    = blockIdx.x >> 8;
  const int hrow = blockIdx.x & 255;

  if (tid < 72){ sst[tid] = 0.f; sqt[tid] = 0.f; }

  // ---- BN scale/shift of the input (4-group parallel shard sum in overlaid LDS) ----
  if constexpr (!RAW){
    int sg = tid >> 7, c = tid & 127;
    if (c < 72){
      float s = 0.f, q = 0.f;
      #pragma unroll
      for (int k2 = 0; k2 < 16; ++k2){
        s += pstat[(sg*16 + k2)*SST + c];
        q += pstat[(sg*16 + k2)*SST + 72 + c];
      }
      pp4[sg*80 + c] = s; pq4[sg*80 + c] = q;
    }
    __syncthreads();
    if (tid < CIN){
      float s = pp4[tid] + pp4[80+tid] + pp4[160+tid] + pp4[240+tid];
      float q = pq4[tid] + pq4[80+tid] + pq4[160+tid] + pq4[240+tid];
      float mean = s * (1.0f/(float)NPC);
      float var  = q * (1.0f/(float)NPC) - mean*mean;
      float scv  = pgam[tid] * rsqrtf(var + BNEPS);
      tsc[tid] = scv;
      tsh[tid] = pbet[tid] - mean*scv;
    }
    __syncthreads();   // tsc/tsh ready; pp4/pq4 (xs head) now dead -> epilogue may reuse
  }

  // ---- MFMA loop: B-fragments direct from global, BN+clip in-register, no barriers ----
  const size_t base_in = (size_t)b*CIN*HWSZ + (size_t)hrow*WCOL;
  const int px0 = wid*32 + li;           // bf0 pixel; bf1 = px0+16 (same 64B line)
  f32x4 acc[5][2];
  #pragma unroll
  for (int mt=0; mt<5; ++mt){ acc[mt][0] = (f32x4){0,0,0,0}; acc[mt][1] = (f32x4){0,0,0,0}; }

  #pragma unroll
  for (int kb2 = 0; kb2 < KB; ++kb2){
    h8 bf0, bf1;
    #pragma unroll
    for (int j = 0; j < 8; ++j){
      int c  = kb2*32 + g*8 + j;
      int cc = (c < CIN) ? c : 0;        // clamp addr; value zeroed below (NaN-safe)
      float v0, v1;
      if constexpr (RAW){
        const float* ip = (const float*)in_ + base_in + (size_t)cc*HWSZ;
        v0 = ip[px0]; v1 = ip[px0 + 16];
      } else {
        const u16* ip = (const u16*)in_ + base_in + (size_t)cc*HWSZ;
        float scv = tsc[cc], shv = tsh[cc];
        v0 = clip8(h2f(ip[px0])*scv + shv);
        v1 = clip8(h2f(ip[px0 + 16])*scv + shv);
      }
      bool ok = (c < CIN);
      bf0[j] = (_Float16)(ok ? v0 : 0.f);
      bf1[j] = (_Float16)(ok ? v1 : 0.f);
    }
    #pragma unroll
    for (int mt = 0; mt < 5; ++mt){
      h8 ah = *(const h8*)(Wp + (size_t)(kb2*80 + mt*16 + li)*40 + g*8);
      acc[mt][0] = __builtin_amdgcn_mfma_f32_16x16x32_f16(ah, bf0, acc[mt][0], 0, 0, 0);
      acc[mt][1] = __builtin_amdgcn_mfma_f32_16x16x32_f16(ah, bf1, acc[mt][1], 0, 0, 0);
    }
  }

  // ---- epilogue: acc -> LDS [72][264] (waves write disjoint px columns) ----
  #pragma unroll
  for (int mt = 0; mt < 5; ++mt){
    int o = mt*16 + g*4;
    if (o < 72){
      #pragma unroll
      for (int t2 = 0; t2 < 2; ++t2){
        int px = wid*32 + t2*16 + li;
        #pragma unroll
        for (int r = 0; r < 4; ++r)
          xs[(o + r)*264 + px] = f2h(acc[mt][t2][r]);
      }
    }
  }
  __syncthreads();

  // ---- readback: coalesced uint4 stores + fused stats ----
  #pragma unroll
  for (int it = 0; it < 5; ++it){
    int e = tid + it*512;
    if (e < 72*32){
      int o = e >> 5, m = e & 31;
      uint4 v = *(const uint4*)&xs[o*264 + m*8];
      u32 rr[4] = {v.x, v.y, v.z, v.w};
      float s = 0.f, q = 0.f;
      #pragma unroll
      for (int q2=0; q2<4; ++q2){
        float a  = h2f((u16)rr[q2]);
        float bq = h2f((u16)(rr[q2]>>16));
        s += a + bq;
        q = fmaf(a,a,q); q = fmaf(bq,bq,q);
      }
      *(uint4*)(out + (size_t)b*CCH*HWSZ + (size_t)o*HWSZ + (size_t)hrow*WCOL + m*8) = v;
      #pragma unroll
      for (int off = 1; off <= 16; off <<= 1){ s += __shfl_xor(s, off); q += __shfl_xor(q, off); }
      if ((lane & 31) == 0){ atomicAdd(&sst[o], s); atomicAdd(&sqt[o], q); }
    }
  }
  __syncthreads();
  if (tid < 72){
    float* oshard = ostat + (size_t)(blockIdx.x & (NSH-1))*SST;
    atomicAdd(oshard + tid,      sst[tid]);
    atomicAdd(oshard + 72 + tid, sqt[tid]);
  }
}

// ---------------- IIR scan along H, fused input BN+ReLU (+optional residual), fp16 IO ----
// R12: W-split x4 — block = 1 wave (64 threads) owning one W-quarter of one (b,c) plane.
// Grid 1152 on 256 CUs => makespan ~1.1x balanced (was 288 blocks => 2x: 32 CUs ran 2 full
// blocks while 224 ran 1). MODE 0: plain. MODE 2: h1 = relu(BN2(in2=y0)) + relu(BN(in)),
// stored to h1buf (h0 recomputed from y0 — no stored-h0 buffer, saves a 37.75MB write).
template<int MODE>
__global__ __launch_bounds__(64) void k_iir(const u16* __restrict__ in, u16* __restrict__ out,
    const float* __restrict__ wabc, u16* __restrict__ h1buf, const u16* __restrict__ in2,
    const float* __restrict__ pstat, const float* __restrict__ pgam, const float* __restrict__ pbet,
    const float* __restrict__ pstat2, const float* __restrict__ pgam2, const float* __restrict__ pbet2,
    float* __restrict__ ostat)
{
  const int tid = threadIdx.x;           // 0..63
  const int wq  = blockIdx.x & 3;        // W-quarter
  const int bc  = blockIdx.x >> 2;       // b*CCH + c
  const int c   = bc % CCH;
  float sc, sh; get_ss_wave(c, tid, pstat, pgam, pbet, sc, sh);
  float sc2 = 0.f, sh2 = 0.f;
  if (MODE==2) get_ss_wave(c, tid, pstat2, pgam2, pbet2, sc2, sh2);
  const float ka = wabc[c], kb = wabc[CCH+c], kcc = wabc[2*CCH+c];
  const size_t base = (size_t)bc*HWSZ + wq*64 + tid;
  float xprev=0.f, yprev=0.f, lsum=0.f, lssq=0.f;

  float a0[16], a1[16], r0[16], r1[16];

  auto LOADC = [&](int hb, float* xv, float* rv){
    #pragma unroll
    for (int j=0;j<16;++j){
      size_t idx = base + (size_t)(hb+j)*WCOL;
      xv[j] = h2f(in[idx]);
      if (MODE==2) rv[j] = h2f(in2[idx]);
    }
  };
  auto COMPC = [&](int hb, const float* xv, const float* rv){
    float x[16];
    #pragma unroll
    for (int j=0;j<16;++j){
      float v = fmaxf(xv[j]*sc + sh, 0.f);
      if (MODE==2){
        v += fmaxf(rv[j]*sc2 + sh2, 0.f);        // + h0 recomputed from y0
        h1buf[base + (size_t)(hb+j)*WCOL] = f2h(v);
      }
      x[j] = v;
    }
    if (hb == 0){ xprev = x[0]; yprev = x[0]; }  // y0 = (a+b+c)*x0
    float t[16];
    t[0] = fmaf(ka, x[0], kb*xprev);
    #pragma unroll
    for (int j=1;j<16;++j) t[j] = fmaf(ka, x[j], kb*x[j-1]);
    #pragma unroll
    for (int j=0;j<16;++j){
      yprev = fmaf(kcc, yprev, t[j]);            // 1-FMA dependent chain
      out[base + (size_t)(hb+j)*WCOL] = f2h(yprev);
      lsum += yprev; lssq = fmaf(yprev,yprev,lssq);
    }
    xprev = x[15];
  };

  LOADC(0, a0, r0);
  #pragma unroll
  for (int hb = 0; hb < HROW; hb += 32){
    LOADC(hb+16, a1, r1);
    COMPC(hb, a0, r0);
    if (hb+32 < HROW) LOADC(hb+32, a0, r0);
    COMPC(hb+16, a1, r1);
  }

  #pragma unroll
  for (int off=32; off; off>>=1){ lsum += __shfl_xor(lsum,off); lssq += __shfl_xor(lssq,off); }
  if (tid==0){
    float* oshard = ostat + (size_t)(blockIdx.x & (NSH-1))*SST;
    atomicAdd(oshard + c,      lsum);
    atomicAdd(oshard + 72 + c, lssq);
  }
}

// ---------------- Depthwise 5-tap along W, fused input BN+clip, fp16 IO ----------
__global__ __launch_bounds__(256) void k_dw(const u16* __restrict__ in, u16* __restrict__ out,
    const float* __restrict__ wgt,
    const float* __restrict__ pstat,
    const float* __restrict__ pgam, const float* __restrict__ pbet,
    float* __restrict__ ostat)
{
  __shared__ float xs[8*264];   // row stride 264, data at col 4+w, zero halo
  __shared__ float rs[4], rq[4];
  const int tid = threadIdx.x;
  const int ht = blockIdx.x & 31;
  const int bc = blockIdx.x >> 5;
  const int c = bc % CCH;
  float sc, sh; get_ss_wave(c, tid&63, pstat, pgam, pbet, sc, sh);
  const float w0=wgt[c*5+0], w1=wgt[c*5+1], w2=wgt[c*5+2], w3=wgt[c*5+3], w4=wgt[c*5+4];
  const size_t base = (size_t)bc*HWSZ + (size_t)ht*(8*WCOL);

  if (tid < 64){
    int r = tid>>3, k = tid&7;
    xs[r*264 + (k<4 ? k : 256+k)] = 0.f;
  }
  const int r = tid >> 5, m = tid & 31;
  {
    uint4 v = *(const uint4*)(in + base + (size_t)r*WCOL + m*8);
    u32 rr[4] = {v.x, v.y, v.z, v.w};
    float f[8];
    #pragma unroll
    for (int q=0;q<4;++q){
      f[2*q]   = clip8(h2f((u16)rr[q])*sc + sh);
      f[2*q+1] = clip8(h2f((u16)(rr[q]>>16))*sc + sh);
    }
    float4* dst = (float4*)&xs[r*264 + 4 + m*8];
    dst[0] = make_float4(f[0],f[1],f[2],f[3]);
    dst[1] = make_float4(f[4],f[5],f[6],f[7]);
  }
  __syncthreads();
  float lsum=0.f, lssq=0.f;
  {
    const float* row = &xs[r*264 + m*8];
    float4 a0 = *(const float4*)(row+0);
    float4 a1 = *(const float4*)(row+4);
    float4 a2 = *(const float4*)(row+8);
    float4 a3 = *(const float4*)(row+12);
    float v[16] = {a0.x,a0.y,a0.z,a0.w, a1.x,a1.y,a1.z,a1.w,
                   a2.x,a2.y,a2.z,a2.w, a3.x,a3.y,a3.z,a3.w};
    float o[8];
    #pragma unroll
    for (int j=0;j<8;++j){
      float y = w0*v[j+2];
      y = fmaf(w1, v[j+3], y);
      y = fmaf(w2, v[j+4], y);
      y = fmaf(w3, v[j+5], y);
      y = fmaf(w4, v[j+6], y);
      o[j] = y;
      lsum += y; lssq = fmaf(y,y,lssq);
    }
    *(uint4*)(out + base + (size_t)r*WCOL + m*8) =
        make_uint4(pack2(o[0],o[1]), pack2(o[2],o[3]), pack2(o[4],o[5]), pack2(o[6],o[7]));
  }
  #pragma unroll
  for (int off=32; off; off>>=1){ lsum += __shfl_xor(lsum,off); lssq += __shfl_xor(lssq,off); }
  if ((tid&63)==0){ rs[tid>>6]=lsum; rq[tid>>6]=lssq; }
  __syncthreads();
  if (tid==0){
    float* oshard = ostat + (size_t)(blockIdx.x & (NSH-1))*SST;
    atomicAdd(oshard + c,      rs[0]+rs[1]+rs[2]+rs[3]);
    atomicAdd(oshard + 72 + c, rq[0]+rq[1]+rq[2]+rq[3]);
  }
}

// ---------------- Final: out = h1 + relu(BN(y12)) (fp32 output) ----------------
__global__ __launch_bounds__(256) void k_final(const u16* __restrict__ y12, const u16* __restrict__ h1,
    float* __restrict__ outp,
    const float* __restrict__ pstat,
    const float* __restrict__ pgam, const float* __restrict__ pbet)
{
  __shared__ float tsc[CCH], tsh[CCH];
  if (threadIdx.x < CCH){
    int cc = threadIdx.x;
    float s=0.f, q=0.f;
    for (int sh2=0; sh2<NSH; ++sh2){ s += pstat[sh2*SST + cc]; q += pstat[sh2*SST + 72 + cc]; }
    float mean = s * (1.0f/(float)NPC);
    float var  = q * (1.0f/(float)NPC) - mean*mean;
    float scv = pgam[cc] * rsqrtf(var + BNEPS);
    tsc[cc] = scv;
    tsh[cc] = pbet[cc] - mean*scv;
  }
  __syncthreads();
  const size_t TOTALQ = (size_t)BBATCH*CCH*HWSZ/4;
  for (size_t q = (size_t)blockIdx.x*blockDim.x + threadIdx.x; q < TOTALQ;
       q += (size_t)gridDim.x*blockDim.x){
    int cch = (int)((q >> 14) % CCH);
    float sc = tsc[cch], sh = tsh[cch];
    uint2 a = *(const uint2*)(y12 + q*4);
    uint2 b = *(const uint2*)(h1 + q*4);
    float4 o;
    o.x = fmaxf(h2f((u16)a.x)*sc+sh, 0.f)       + h2f((u16)b.x);
    o.y = fmaxf(h2f((u16)(a.x>>16))*sc+sh, 0.f) + h2f((u16)(b.x>>16));
    o.z = fmaxf(h2f((u16)a.y)*sc+sh, 0.f)       + h2f((u16)b.y);
    o.w = fmaxf(h2f((u16)(a.y>>16))*sc+sh, 0.f) + h2f((u16)(b.y>>16));
    *(float4*)(outp + q*4) = o;
  }
}

extern "C" void kernel_launch(void* const* d_in, const int* in_sizes, int n_in,
                              void* d_out, int out_size, void* d_ws, size_t ws_size,
                              hipStream_t stream)
{
  (void)in_sizes; (void)n_in; (void)out_size;
  const float* x   = (const float*)d_in[0];
  const float* ew  = (const float*)d_in[1];
  const float* eg  = (const float*)d_in[3];
  const float* ebt = (const float*)d_in[4];
  const float* iw  = (const float*)d_in[5];
  const float* ig  = (const float*)d_in[6];
  const float* ibt = (const float*)d_in[7];
  const float* dwt = (const float*)d_in[8];
  const float* dg  = (const float*)d_in[10];
  const float* dbt = (const float*)d_in[11];
  const float* pw  = (const float*)d_in[12];
  const float* pg  = (const float*)d_in[14];
  const float* pbt = (const float*)d_in[15];
  float* outp = (float*)d_out;

  const size_t BUFE = (size_t)BBATCH*CCH*HWSZ;     // 18,874,368 elements
  const size_t BUFB = BUFE*2;                      // fp16: 37.75 MB per buffer
  const size_t STATSB = (size_t)13*NSH*SST*sizeof(float);  // ~479 KB
  const size_t WPB = (size_t)14*3200*sizeof(u16);  // 89.6 KB prepped weights
  char* ws = (char*)d_ws;
  // A holds y0 for the whole pipeline (unit-2 IIR recomputes h0 from it).
  u16* A = (u16*)ws;
  u16* C = (u16*)(ws + BUFB);
  u16* H = (u16*)(ws + 2*BUFB);                    // h1 buffer
  float* stats = (float*)(ws + 3*BUFB);
  u16* Wp = (u16*)((char*)stats + STATSB);
  u16* B;
  if (ws_size >= 4*BUFB + STATSB + WPB + 256){
    B = (u16*)((char*)Wp + ((WPB+255)&~(size_t)255));
  } else {
    // B lives in d_out (dead before k_final, which reads C and H only)
    B = (u16*)d_out;
  }
  #define ST(s) (stats + (size_t)(s)*NSH*SST)
  #define WSLAB(u) (Wp + (size_t)(2 + 3*(u))*3200)

  hipMemsetAsync(stats, 0, STATSB, stream);

  dim3 blk(256);
  dim3 blkpw(512);
  dim3 blkiir(64);
  const int GIIR = BBATCH*CCH*4;   // W-split x4
  k_prep<<<18, blk, 0, stream>>>(ew, pw, Wp);
  // s0: expand pointwise (fp32 x -> y0 in A), raw stats0
  k_pw<36,1><<<BBATCH*HROW, blkpw, 0, stream>>>((const void*)x, A, Wp,
      nullptr, nullptr, nullptr, ST(0));
  // unit 0  (A preserved as y0)
  k_iir<0><<<GIIR, blkiir, 0, stream>>>(A, B, iw+0, nullptr, nullptr,
      ST(0), eg, ebt, nullptr, nullptr, nullptr, ST(1));
  k_dw    <<<BBATCH*CCH*32, blk, 0, stream>>>(B, C, dwt+0,    ST(1), ig+0,   ibt+0,   ST(2));
  k_pw<72,0><<<BBATCH*HROW, blkpw, 0, stream>>>(C, B, WSLAB(0), ST(2), dg+0,   dbt+0,   ST(3));
  // unit 1
  k_iir<0><<<GIIR, blkiir, 0, stream>>>(B, C, iw+216, nullptr, nullptr,
      ST(3), pg+0, pbt+0, nullptr, nullptr, nullptr, ST(4));
  k_dw    <<<BBATCH*CCH*32, blk, 0, stream>>>(C, B, dwt+360,  ST(4), ig+72,  ibt+72,  ST(5));
  k_pw<72,0><<<BBATCH*HROW, blkpw, 0, stream>>>(B, C, WSLAB(1), ST(5), dg+72,  dbt+72,  ST(6));
  // unit 2: h1 = relu(BN0(y0=A)) + relu(BN6(y6=C)) -> H; IIR(h1) -> B
  k_iir<2><<<GIIR, blkiir, 0, stream>>>(C, B, iw+432, H, A,
      ST(6), pg+72, pbt+72, ST(0), eg, ebt, ST(7));
  k_dw    <<<BBATCH*CCH*32, blk, 0, stream>>>(B, C, dwt+720,  ST(7), ig+144, ibt+144, ST(8));
  k_pw<72,0><<<BBATCH*HROW, blkpw, 0, stream>>>(C, B, WSLAB(2), ST(8), dg+144, dbt+144, ST(9));
  // unit 3
  k_iir<0><<<GIIR, blkiir, 0, stream>>>(B, C, iw+648, nullptr, nullptr,
      ST(9), pg+144, pbt+144, nullptr, nullptr, nullptr, ST(10));
  k_dw    <<<BBATCH*CCH*32, blk, 0, stream>>>(C, B, dwt+1080, ST(10), ig+216, ibt+216, ST(11));
  k_pw<72,0><<<BBATCH*HROW, blkpw, 0, stream>>>(B, C, WSLAB(3), ST(11), dg+216, dbt+216, ST(12));
  // out = h1 + relu(BN12(y12))
  k_final<<<2048, blk, 0, stream>>>(C, H, outp, ST(12), pg+216, pbt+216);
  #undef ST
  #undef WSLAB
}